// Round 1
// baseline (4182.806 us; speedup 1.0000x reference)
//
#include <hip/hip_runtime.h>
#include <cstdint>

typedef unsigned short ushort_t;
typedef short v8s __attribute__((ext_vector_type(8)));
typedef float v4f __attribute__((ext_vector_type(4)));
typedef unsigned short v4u __attribute__((ext_vector_type(4)));

#define DMODEL 1024
#define DFF 4096
#define SEQ 4096
#define NBATCH 4
#define NHEAD 16
#define HDIM 64
#define NLAYER 4
#define MTOK (NBATCH*SEQ)   // 16384

#define EPI_V 0
#define EPI_Q 1
#define EPI_K 2
#define EPI_RES 3
#define EPI_GELU 4

__device__ __forceinline__ float bf2f(ushort_t u) {
    unsigned v = ((unsigned)u) << 16; float f; __builtin_memcpy(&f, &v, 4); return f;
}
__device__ __forceinline__ ushort_t f2bf(float f) {
    unsigned u; __builtin_memcpy(&u, &f, 4);
    u = (u + 0x7fffu + ((u >> 16) & 1u)) >> 16;
    return (ushort_t)u;
}

// ---------------------------------------------------------------------------
// fp32 -> bf16 conversion (vectorized, n multiple of 1024)
// ---------------------------------------------------------------------------
__global__ __launch_bounds__(256) void cvt_bf16(const float* __restrict__ in,
                                                ushort_t* __restrict__ out, int n) {
    int i = (blockIdx.x * 256 + threadIdx.x) * 4;
    if (i >= n) return;
    float4 v = *(const float4*)(in + i);
    v4u o;
    o[0] = f2bf(v.x); o[1] = f2bf(v.y); o[2] = f2bf(v.z); o[3] = f2bf(v.w);
    *(v4u*)(out + i) = o;
}

// ---------------------------------------------------------------------------
// lens[b] = SEQ - count_nonzero(mask[b,:])  (mask read as bytes; all-zero in test)
// ---------------------------------------------------------------------------
__global__ __launch_bounds__(256) void lens_kernel(const unsigned char* __restrict__ mask,
                                                   int* __restrict__ lens) {
    int lane = threadIdx.x & 63, w = threadIdx.x >> 6;  // wave per batch
    int cnt = 0;
    for (int i = lane; i < SEQ; i += 64) cnt += (mask[w * SEQ + i] != 0) ? 1 : 0;
    #pragma unroll
    for (int off = 32; off; off >>= 1) cnt += __shfl_down(cnt, off);
    if (lane == 0) lens[w] = SEQ - cnt;
}

// ---------------------------------------------------------------------------
// GEMM: C[M,N] = A[M,K] @ B[N,K]^T, bf16 inputs, fp32 accumulate, fused epilogue.
// 128x128 tile, 4 waves each 64x64 (4x4 grid of 16x16x32 MFMA), BK=32,
// global_load_lds width-16 staging (m97 structure).
// ---------------------------------------------------------------------------
template <int EPI>
__global__ __launch_bounds__(256) void gemm_bt(
    const ushort_t* __restrict__ A, const ushort_t* __restrict__ B,
    const float* __restrict__ bias, const float* res,
    const int* __restrict__ lens,
    ushort_t* __restrict__ outB, float* outF,
    int M, int N, int K)
{
    __shared__ __align__(16) ushort_t As[128 * 32];
    __shared__ __align__(16) ushort_t Bs[128 * 32];

    const int tid = threadIdx.x;
    const int lane = tid & 63;
    const int wave = tid >> 6;
    const int nb = N >> 7;
    const int bm = blockIdx.x / nb;
    const int bn = blockIdx.x % nb;
    const int wm = (wave >> 1) * 64;
    const int wn = (wave & 1) * 64;
    const int lr = lane & 15;
    const int lq = lane >> 4;  // 0..3

    v4f acc[4][4];
    #pragma unroll
    for (int i = 0; i < 4; i++)
        #pragma unroll
        for (int j = 0; j < 4; j++) acc[i][j] = (v4f)0.f;

    const ushort_t* Ag = A + (size_t)(bm * 128 + (tid >> 2)) * K + (tid & 3) * 8;
    const ushort_t* Bg = B + (size_t)(bn * 128 + (tid >> 2)) * K + (tid & 3) * 8;
    ushort_t* Asp = As + tid * 8;   // 16B per thread, LDS dest = wave base + lane*16
    ushort_t* Bsp = Bs + tid * 8;

    for (int k0 = 0; k0 < K; k0 += 32) {
        __builtin_amdgcn_global_load_lds((const void*)(Ag + k0), (void*)Asp, 16, 0, 0);
        __builtin_amdgcn_global_load_lds((const void*)(Ag + (size_t)64 * K + k0), (void*)(Asp + 2048), 16, 0, 0);
        __builtin_amdgcn_global_load_lds((const void*)(Bg + k0), (void*)Bsp, 16, 0, 0);
        __builtin_amdgcn_global_load_lds((const void*)(Bg + (size_t)64 * K + k0), (void*)(Bsp + 2048), 16, 0, 0);
        __syncthreads();   // drains vmcnt, makes LDS visible

        v8s af[4], bfr[4];
        #pragma unroll
        for (int i = 0; i < 4; i++)
            af[i] = *(const v8s*)&As[(wm + i * 16 + lr) * 32 + lq * 8];
        #pragma unroll
        for (int j = 0; j < 4; j++)
            bfr[j] = *(const v8s*)&Bs[(wn + j * 16 + lr) * 32 + lq * 8];
        #pragma unroll
        for (int i = 0; i < 4; i++)
            #pragma unroll
            for (int j = 0; j < 4; j++)
                acc[i][j] = __builtin_amdgcn_mfma_f32_16x16x32_bf16(af[i], bfr[j], acc[i][j], 0, 0, 0);
        __syncthreads();   // protect LDS from next iteration's overwrite
    }

    // epilogue: C/D layout col = lane&15, row = (lane>>4)*4 + reg
    const int row0 = bm * 128 + wm + lq * 4;
    const int col0 = bn * 128 + wn + lr;
    #pragma unroll
    for (int i = 0; i < 4; i++) {
        #pragma unroll
        for (int j = 0; j < 4; j++) {
            const int gn = col0 + j * 16;
            const float bsv = bias[gn];
            #pragma unroll
            for (int r = 0; r < 4; r++) {
                const int gm = row0 + i * 16 + r;
                float v = acc[i][j][r] + bsv;
                const size_t oi = (size_t)gm * N + gn;
                if (EPI == EPI_Q) {
                    outB[oi] = f2bf(v > 0.f ? v + 1.f : __expf(v));
                } else if (EPI == EPI_K) {
                    float e = v > 0.f ? v + 1.f : __expf(v);
                    const int b = gm >> 12, s = gm & 4095;
                    if (s >= lens[b]) e = 0.f;
                    outB[oi] = f2bf(e);
                } else if (EPI == EPI_V) {
                    outB[oi] = f2bf(v);
                } else if (EPI == EPI_RES) {
                    outF[oi] = v + res[oi];
                } else {  // EPI_GELU (exact)
                    outB[oi] = f2bf(0.5f * v * (1.f + erff(v * 0.70710678118f)));
                }
            }
        }
    }
}

// ---------------------------------------------------------------------------
// Ksum[n, c] = sum_s K[n, s, c]   (c = h*64+d), fp32 accumulate
// grid 64 = (n,colgroup of 64); block 256 = 4 s-chunks x 64 cols
// ---------------------------------------------------------------------------
__global__ __launch_bounds__(256) void ksum_kernel(const ushort_t* __restrict__ K,
                                                   float* __restrict__ out) {
    const int blk = blockIdx.x;
    const int n = blk >> 4, cg = blk & 15;
    const int tx = threadIdx.x & 63, ty = threadIdx.x >> 6;
    const int col = cg * 64 + tx;
    const ushort_t* p = K + ((size_t)n * SEQ + ty * 1024) * DMODEL + col;
    float a = 0.f;
    for (int s = 0; s < 1024; s++) a += bf2f(p[(size_t)s * DMODEL]);
    __shared__ float red[4][64];
    red[ty][tx] = a;
    __syncthreads();
    if (ty == 0) out[n * DMODEL + col] = red[0][tx] + red[1][tx] + red[2][tx] + red[3][tx];
}

// ---------------------------------------------------------------------------
// Z[t,h] = 1 / (Q[t,h,:] . Ksum[n,h,:] + eps)
// ---------------------------------------------------------------------------
__global__ __launch_bounds__(256) void z_kernel(const ushort_t* __restrict__ Q,
                                                const float* __restrict__ Ksum,
                                                float* __restrict__ Z) {
    const int gid = blockIdx.x * 256 + threadIdx.x;
    const int t = gid >> 4, h = gid & 15, n = t >> 12;
    const v4u* q4 = (const v4u*)(Q + (size_t)t * DMODEL + h * HDIM);
    const float4* k4 = (const float4*)(Ksum + n * DMODEL + h * HDIM);
    float acc = 0.f;
    #pragma unroll
    for (int d = 0; d < 16; d++) {
        v4u u = q4[d]; float4 kk = k4[d];
        acc += bf2f(u[0]) * kk.x + bf2f(u[1]) * kk.y + bf2f(u[2]) * kk.z + bf2f(u[3]) * kk.w;
    }
    Z[gid] = 1.f / (acc + 1e-6f);
}

// ---------------------------------------------------------------------------
// KV partials: part[chunk, nh, m, d] = sum_{s in chunk} V[s,m] * K[s,d]
// grid (8 chunks, 64 nh); block 256 = 16x16, each thread a 4x4 tile
// ---------------------------------------------------------------------------
__global__ __launch_bounds__(256) void kv_part(const ushort_t* __restrict__ K,
                                               const ushort_t* __restrict__ V,
                                               float* __restrict__ part) {
    const int chunk = blockIdx.x, nh = blockIdx.y;
    const int n = nh >> 4, h = nh & 15;
    const int tid = threadIdx.x;
    const int tm = tid >> 4, td = tid & 15;
    __shared__ float Ks[16][68];
    __shared__ float Vs[16][68];
    float acc[4][4] = {};
    const int s0 = chunk * 512;
    for (int sb = 0; sb < 512; sb += 16) {
        __syncthreads();
        for (int idx = tid; idx < 1024; idx += 256) {
            const int r = idx >> 6, c = idx & 63;
            const size_t gpos = ((size_t)(n * SEQ + s0 + sb + r)) * DMODEL + h * HDIM + c;
            Ks[r][c] = bf2f(K[gpos]);
            Vs[r][c] = bf2f(V[gpos]);
        }
        __syncthreads();
        #pragma unroll
        for (int s = 0; s < 16; s++) {
            float kv[4], vv[4];
            #pragma unroll
            for (int j = 0; j < 4; j++) kv[j] = Ks[s][td * 4 + j];
            #pragma unroll
            for (int i = 0; i < 4; i++) vv[i] = Vs[s][tm * 4 + i];
            #pragma unroll
            for (int i = 0; i < 4; i++)
                #pragma unroll
                for (int j = 0; j < 4; j++)
                    acc[i][j] += vv[i] * kv[j];
        }
    }
    float* o = part + ((size_t)chunk * 64 + nh) * 4096;
    #pragma unroll
    for (int i = 0; i < 4; i++)
        #pragma unroll
        for (int j = 0; j < 4; j++)
            o[(tm * 4 + i) * 64 + td * 4 + j] = acc[i][j];
}

__global__ __launch_bounds__(256) void kv_reduce(const float* __restrict__ part,
                                                 float* __restrict__ KV) {
    const int gid = blockIdx.x * 256 + threadIdx.x;
    float a = 0.f;
    #pragma unroll
    for (int c = 0; c < 8; c++) a += part[(size_t)c * (64 * 4096) + gid];
    KV[gid] = a;
}

// ---------------------------------------------------------------------------
// attn[t, h*64+m] = Z[t,h] * sum_d Q[t,h,d] * KV[nh,m,d]
// grid (64 row-tiles, 64 nh); block 256 = 16x16, each thread 4 rows x 4 cols
// ---------------------------------------------------------------------------
__global__ __launch_bounds__(256) void attn_kernel(const ushort_t* __restrict__ Q,
                                                   const float* __restrict__ KV,
                                                   const float* __restrict__ Z,
                                                   ushort_t* __restrict__ out) {
    const int bx = blockIdx.x, nh = blockIdx.y;
    const int n = nh >> 4, h = nh & 15;
    const int tid = threadIdx.x;
    const int ty = tid >> 4, tx = tid & 15;
    __shared__ float KVs[64][65];
    __shared__ float Qs[64][65];
    __shared__ float Zs[64];
    const int t0 = n * SEQ + bx * 64;
    for (int idx = tid; idx < 4096; idx += 256) {
        const int r = idx >> 6, c = idx & 63;
        KVs[r][c] = KV[(size_t)nh * 4096 + idx];
        Qs[r][c] = bf2f(Q[((size_t)(t0 + r)) * DMODEL + h * HDIM + c]);
    }
    if (tid < 64) Zs[tid] = Z[(t0 + tid) * NHEAD + h];
    __syncthreads();
    float acc[4][4] = {};
    for (int d = 0; d < 64; d++) {
        float qv[4], kv[4];
        #pragma unroll
        for (int i = 0; i < 4; i++) qv[i] = Qs[ty * 4 + i][d];
        #pragma unroll
        for (int j = 0; j < 4; j++) kv[j] = KVs[tx * 4 + j][d];
        #pragma unroll
        for (int i = 0; i < 4; i++)
            #pragma unroll
            for (int j = 0; j < 4; j++)
                acc[i][j] += qv[i] * kv[j];
    }
    #pragma unroll
    for (int i = 0; i < 4; i++) {
        const int r = ty * 4 + i;
        const float z = Zs[r];
        #pragma unroll
        for (int j = 0; j < 4; j++)
            out[((size_t)(t0 + r)) * DMODEL + h * HDIM + tx * 4 + j] = f2bf(acc[i][j] * z);
    }
}

// ---------------------------------------------------------------------------
// LayerNorm over D=1024: outF = LN(in)*g+b (fp32, may be in-place),
// optional bf16 copy to outB.
// ---------------------------------------------------------------------------
__global__ __launch_bounds__(256) void ln_kernel(const float* in, float* outF,
                                                 ushort_t* outB,
                                                 const float* __restrict__ g,
                                                 const float* __restrict__ b) {
    const int row = blockIdx.x;
    const int tid = threadIdx.x;
    const float4 v = ((const float4*)(in + (size_t)row * DMODEL))[tid];
    float s = v.x + v.y + v.z + v.w;
    float ss = v.x * v.x + v.y * v.y + v.z * v.z + v.w * v.w;
    #pragma unroll
    for (int off = 32; off; off >>= 1) {
        s += __shfl_down(s, off);
        ss += __shfl_down(ss, off);
    }
    __shared__ float red[8];
    const int lane = tid & 63, w = tid >> 6;
    if (lane == 0) { red[w * 2] = s; red[w * 2 + 1] = ss; }
    __syncthreads();
    s = red[0] + red[2] + red[4] + red[6];
    ss = red[1] + red[3] + red[5] + red[7];
    const float mu = s * (1.f / DMODEL);
    const float var = ss * (1.f / DMODEL) - mu * mu;
    const float rs = rsqrtf(var + 1e-5f);
    const float4 gg = ((const float4*)g)[tid];
    const float4 bb = ((const float4*)b)[tid];
    float4 o;
    o.x = (v.x - mu) * rs * gg.x + bb.x;
    o.y = (v.y - mu) * rs * gg.y + bb.y;
    o.z = (v.z - mu) * rs * gg.z + bb.z;
    o.w = (v.w - mu) * rs * gg.w + bb.w;
    ((float4*)(outF + (size_t)row * DMODEL))[tid] = o;
    if (outB) {
        v4u ob;
        ob[0] = f2bf(o.x); ob[1] = f2bf(o.y); ob[2] = f2bf(o.z); ob[3] = f2bf(o.w);
        *(v4u*)(outB + (size_t)row * DMODEL + tid * 4) = ob;
    }
}

// ---------------------------------------------------------------------------
extern "C" void kernel_launch(void* const* d_in, const int* in_sizes, int n_in,
                              void* d_out, int out_size, void* d_ws, size_t ws_size,
                              hipStream_t stream) {
    const float* src = (const float*)d_in[0];
    const unsigned char* mask = (const unsigned char*)d_in[1];
    const float* Wq = (const float*)d_in[2];
    const float* bq = (const float*)d_in[3];
    const float* Wk = (const float*)d_in[4];
    const float* bk = (const float*)d_in[5];
    const float* Wv = (const float*)d_in[6];
    const float* bv = (const float*)d_in[7];
    const float* Wo = (const float*)d_in[8];
    const float* bo = (const float*)d_in[9];
    const float* W1 = (const float*)d_in[10];
    const float* b1 = (const float*)d_in[11];
    const float* W2 = (const float*)d_in[12];
    const float* b2 = (const float*)d_in[13];
    const float* g1 = (const float*)d_in[14];
    const float* be1 = (const float*)d_in[15];
    const float* g2 = (const float*)d_in[16];
    const float* be2 = (const float*)d_in[17];

    float* xout = (float*)d_out;  // fp32 residual-stream master lives in d_out

    char* ws = (char*)d_ws;
    size_t off = 0;
    auto alloc = [&](size_t bytes) -> void* {
        void* p = (void*)(ws + off);
        off += (bytes + 255) & ~(size_t)255;
        return p;
    };
    const size_t DD = (size_t)DMODEL * DMODEL;  // 1,048,576
    const size_t FD = (size_t)DFF * DMODEL;     // 4,194,304
    const size_t MD = (size_t)MTOK * DMODEL;    // 16,777,216

    ushort_t* wq_bf = (ushort_t*)alloc(NLAYER * DD * 2);
    ushort_t* wk_bf = (ushort_t*)alloc(NLAYER * DD * 2);
    ushort_t* wv_bf = (ushort_t*)alloc(NLAYER * DD * 2);
    ushort_t* wo_bf = (ushort_t*)alloc(NLAYER * DD * 2);
    ushort_t* w1r = (ushort_t*)alloc(FD * 2);   // rotating per-layer FFN weights
    ushort_t* w2r = (ushort_t*)alloc(FD * 2);
    ushort_t* xbf = (ushort_t*)alloc(MD * 2);
    ushort_t* Qb = (ushort_t*)alloc(MD * 2);
    ushort_t* Kb = (ushort_t*)alloc(MD * 2);
    ushort_t* Vb = (ushort_t*)alloc(MD * 2);
    (void)alloc(MD * 2);          // extension: hb (=Qb) spans MTOK*DFF bf16
    ushort_t* hb = Qb;
    float* Ksum = (float*)alloc((size_t)NBATCH * DMODEL * 4);
    float* Zbuf = (float*)alloc((size_t)MTOK * NHEAD * 4);
    float* KVp = (float*)alloc((size_t)8 * 64 * 4096 * 4);
    float* KVb = (float*)alloc((size_t)64 * 4096 * 4);
    int* lens = (int*)alloc(256);
    if (off > ws_size) return;  // insufficient workspace — bail (will fail validation loudly)

    // convert all Q/K/V/O weights once; FFN weights rotate per layer
    cvt_bf16<<<dim3((unsigned)((NLAYER * DD) / 1024)), dim3(256), 0, stream>>>(Wq, wq_bf, (int)(NLAYER * DD));
    cvt_bf16<<<dim3((unsigned)((NLAYER * DD) / 1024)), dim3(256), 0, stream>>>(Wk, wk_bf, (int)(NLAYER * DD));
    cvt_bf16<<<dim3((unsigned)((NLAYER * DD) / 1024)), dim3(256), 0, stream>>>(Wv, wv_bf, (int)(NLAYER * DD));
    cvt_bf16<<<dim3((unsigned)((NLAYER * DD) / 1024)), dim3(256), 0, stream>>>(Wo, wo_bf, (int)(NLAYER * DD));
    lens_kernel<<<dim3(1), dim3(256), 0, stream>>>(mask, lens);
    cvt_bf16<<<dim3((unsigned)(MD / 1024)), dim3(256), 0, stream>>>(src, xbf, (int)MD);

    const dim3 blk(256);
    const dim3 gD((MTOK / 128) * (DMODEL / 128));  // 1024 blocks (N=1024)
    const dim3 gF((MTOK / 128) * (DFF / 128));     // 4096 blocks (N=4096)

    for (int l = 0; l < NLAYER; l++) {
        const ushort_t* wql = wq_bf + l * DD;
        const ushort_t* wkl = wk_bf + l * DD;
        const ushort_t* wvl = wv_bf + l * DD;
        const ushort_t* wol = wo_bf + l * DD;
        const float* bql = bq + l * DMODEL;
        const float* bkl = bk + l * DMODEL;
        const float* bvl = bv + l * DMODEL;
        const float* bol = bo + l * DMODEL;
        const float* b1l = b1 + l * DFF;
        const float* b2l = b2 + l * DMODEL;
        const float* g1l = g1 + l * DMODEL;
        const float* be1l = be1 + l * DMODEL;
        const float* g2l = g2 + l * DMODEL;
        const float* be2l = be2 + l * DMODEL;
        const float* resx = (l == 0) ? src : xout;

        // Q/K/V projections with fused feature map
        gemm_bt<EPI_Q><<<gD, blk, 0, stream>>>(xbf, wql, bql, nullptr, lens, Qb, nullptr, MTOK, DMODEL, DMODEL);
        gemm_bt<EPI_K><<<gD, blk, 0, stream>>>(xbf, wkl, bkl, nullptr, lens, Kb, nullptr, MTOK, DMODEL, DMODEL);
        gemm_bt<EPI_V><<<gD, blk, 0, stream>>>(xbf, wvl, bvl, nullptr, lens, Vb, nullptr, MTOK, DMODEL, DMODEL);

        // linear-attention core
        ksum_kernel<<<dim3(64), blk, 0, stream>>>(Kb, Ksum);
        z_kernel<<<dim3(MTOK * NHEAD / 256), blk, 0, stream>>>(Qb, Ksum, Zbuf);
        kv_part<<<dim3(8, 64), blk, 0, stream>>>(Kb, Vb, KVp);
        kv_reduce<<<dim3(64 * 4096 / 256), blk, 0, stream>>>(KVp, KVb);
        attn_kernel<<<dim3(64, 64), blk, 0, stream>>>(Qb, KVb, Zbuf, Kb);  // attn -> Kb (K dead)

        // output projection + residual (fp32), then LN1 (in-place) + bf16 copy
        gemm_bt<EPI_RES><<<gD, blk, 0, stream>>>(Kb, wol, bol, resx, lens, nullptr, xout, MTOK, DMODEL, DMODEL);
        ln_kernel<<<dim3(MTOK), blk, 0, stream>>>(xout, xout, xbf, g1l, be1l);

        // FFN
        cvt_bf16<<<dim3((unsigned)(FD / 1024)), blk, 0, stream>>>(W1 + l * FD, w1r, (int)FD);
        gemm_bt<EPI_GELU><<<gF, blk, 0, stream>>>(xbf, w1r, b1l, nullptr, lens, hb, nullptr, MTOK, DFF, DMODEL);
        cvt_bf16<<<dim3((unsigned)(FD / 1024)), blk, 0, stream>>>(W2 + l * FD, w2r, (int)FD);
        gemm_bt<EPI_RES><<<gD, blk, 0, stream>>>(hb, w2r, b2l, xout, lens, nullptr, xout, MTOK, DMODEL, DFF);
        ln_kernel<<<dim3(MTOK), blk, 0, stream>>>(xout, xout, (l == NLAYER - 1) ? nullptr : xbf, g2l, be2l);
    }
}

// Round 2
// 3977.692 us; speedup vs baseline: 1.0516x; 1.0516x over previous
//
#include <hip/hip_runtime.h>
#include <cstdint>

typedef unsigned short ushort_t;
typedef short v8s __attribute__((ext_vector_type(8)));
typedef float v4f __attribute__((ext_vector_type(4)));
typedef unsigned short v4u __attribute__((ext_vector_type(4)));

#define DMODEL 1024
#define DFF 4096
#define SEQ 4096
#define NBATCH 4
#define NHEAD 16
#define HDIM 64
#define NLAYER 4
#define MTOK (NBATCH*SEQ)   // 16384

#define EPI_QKV 0
#define EPI_RES 3
#define EPI_GELU 4

__device__ __forceinline__ float bf2f(ushort_t u) {
    unsigned v = ((unsigned)u) << 16; float f; __builtin_memcpy(&f, &v, 4); return f;
}
__device__ __forceinline__ ushort_t f2bf(float f) {
    unsigned u; __builtin_memcpy(&u, &f, 4);
    u = (u + 0x7fffu + ((u >> 16) & 1u)) >> 16;
    return (ushort_t)u;
}

// ---------------------------------------------------------------------------
// fp32 -> bf16 conversion (vectorized, n multiple of 1024)
// ---------------------------------------------------------------------------
__global__ __launch_bounds__(256) void cvt_bf16(const float* __restrict__ in,
                                                ushort_t* __restrict__ out, int n) {
    int i = (blockIdx.x * 256 + threadIdx.x) * 4;
    if (i >= n) return;
    float4 v = *(const float4*)(in + i);
    v4u o;
    o[0] = f2bf(v.x); o[1] = f2bf(v.y); o[2] = f2bf(v.z); o[3] = f2bf(v.w);
    *(v4u*)(out + i) = o;
}

// pack Wq/Wk/Wv (each [L][D][D] fp32) into bf16 [L][3][D][D]
__global__ __launch_bounds__(256) void cvt_qkv(const float* __restrict__ Wq,
                                               const float* __restrict__ Wk,
                                               const float* __restrict__ Wv,
                                               ushort_t* __restrict__ out) {
    const size_t DD = (size_t)DMODEL * DMODEL;
    size_t i = ((size_t)blockIdx.x * 256 + threadIdx.x) * 4;   // i < L*DD
    int l = (int)(i / DD);
    size_t r = i % DD;
    const float* srcs[3] = { Wq + l * DD + r, Wk + l * DD + r, Wv + l * DD + r };
    #pragma unroll
    for (int s = 0; s < 3; s++) {
        float4 v = *(const float4*)srcs[s];
        v4u o;
        o[0] = f2bf(v.x); o[1] = f2bf(v.y); o[2] = f2bf(v.z); o[3] = f2bf(v.w);
        *(v4u*)(out + ((size_t)l * 3 + s) * DD + r) = o;
    }
}

// ---------------------------------------------------------------------------
// lens[b] = SEQ - count_nonzero(mask[b,:])
// ---------------------------------------------------------------------------
__global__ __launch_bounds__(256) void lens_kernel(const unsigned char* __restrict__ mask,
                                                   int* __restrict__ lens) {
    int lane = threadIdx.x & 63, w = threadIdx.x >> 6;
    int cnt = 0;
    for (int i = lane; i < SEQ; i += 64) cnt += (mask[w * SEQ + i] != 0) ? 1 : 0;
    #pragma unroll
    for (int off = 32; off; off >>= 1) cnt += __shfl_down(cnt, off);
    if (lane == 0) lens[w] = SEQ - cnt;
}

// ---------------------------------------------------------------------------
// GEMM: C[M,N] = A[M,K] @ B[N,K]^T, bf16 in, fp32 acc, fused epilogues.
// 128x128 tile, 4 waves of 64x64, BK=32, global_load_lds width-16.
// XCD-aware block remap: same-bm blocks share an XCD (A-tile L2 reuse).
// LDS k-chunk XOR swizzle kills the 8-way bank conflict of the m97 layout.
// ---------------------------------------------------------------------------
template <int EPI>
__global__ __launch_bounds__(256) void gemm_bt(
    const ushort_t* __restrict__ A, const ushort_t* __restrict__ B,
    const float* __restrict__ bias, const float* __restrict__ bias2,
    const float* __restrict__ bias3, const float* res,
    const int* __restrict__ lens,
    ushort_t* __restrict__ outB, ushort_t* __restrict__ outB2,
    ushort_t* __restrict__ outB3, float* outF,
    int M, int N, int K)
{
    __shared__ __align__(16) ushort_t As[128 * 32];
    __shared__ __align__(16) ushort_t Bs[128 * 32];

    const int tid = threadIdx.x;
    const int lane = tid & 63;
    const int wave = tid >> 6;
    const int nb = N >> 7;
    // XCD-aware remap: dispatch round-robins XCD = blockIdx.x % 8.
    // Blocks with equal bm get equal (blockIdx.x & 7) -> same XCD.
    const int xcd = blockIdx.x & 7;
    const int q = blockIdx.x >> 3;
    const int bm = (q / nb) * 8 + xcd;   // M/128 = 128, divisible by 8
    const int bn = q % nb;
    const int wm = (wave >> 1) * 64;
    const int wn = (wave & 1) * 64;
    const int lr = lane & 15;
    const int lq = lane >> 4;  // 0..3

    v4f acc[4][4];
    #pragma unroll
    for (int i = 0; i < 4; i++)
        #pragma unroll
        for (int j = 0; j < 4; j++) acc[i][j] = (v4f)0.f;

    // staging: thread tid covers row srow (and srow+64), k-chunk (tid&3), but
    // fetches the XOR-swizzled global chunk so LDS position c holds global
    // chunk c ^ ((row>>1)&3).
    const int srow = tid >> 2;
    const int schunk = (tid & 3) ^ ((srow >> 1) & 3);
    const ushort_t* Ag = A + (size_t)(bm * 128 + srow) * K + schunk * 8;
    const ushort_t* Bg = B + (size_t)(bn * 128 + srow) * K + schunk * 8;
    ushort_t* Asp = As + tid * 8;
    ushort_t* Bsp = Bs + tid * 8;

    // fragment LDS addresses (k-invariant; includes the read-side XOR)
    int a_off[4], b_off[4];
    #pragma unroll
    for (int i = 0; i < 4; i++) {
        const int ra = wm + i * 16 + lr;
        a_off[i] = ra * 32 + ((lq ^ ((ra >> 1) & 3)) * 8);
        const int rb = wn + i * 16 + lr;
        b_off[i] = rb * 32 + ((lq ^ ((rb >> 1) & 3)) * 8);
    }

    for (int k0 = 0; k0 < K; k0 += 32) {
        __builtin_amdgcn_global_load_lds((const void*)(Ag + k0), (void*)Asp, 16, 0, 0);
        __builtin_amdgcn_global_load_lds((const void*)(Ag + (size_t)64 * K + k0), (void*)(Asp + 2048), 16, 0, 0);
        __builtin_amdgcn_global_load_lds((const void*)(Bg + k0), (void*)Bsp, 16, 0, 0);
        __builtin_amdgcn_global_load_lds((const void*)(Bg + (size_t)64 * K + k0), (void*)(Bsp + 2048), 16, 0, 0);
        __syncthreads();

        v8s af[4], bfr[4];
        #pragma unroll
        for (int i = 0; i < 4; i++) af[i] = *(const v8s*)&As[a_off[i]];
        #pragma unroll
        for (int j = 0; j < 4; j++) bfr[j] = *(const v8s*)&Bs[b_off[j]];
        #pragma unroll
        for (int i = 0; i < 4; i++)
            #pragma unroll
            for (int j = 0; j < 4; j++)
                acc[i][j] = __builtin_amdgcn_mfma_f32_16x16x32_bf16(af[i], bfr[j], acc[i][j], 0, 0, 0);
        __syncthreads();
    }

    // epilogue: C/D layout col = lane&15, row = (lane>>4)*4 + reg
    const int row0 = bm * 128 + wm + lq * 4;
    const int col0 = bn * 128 + wn + lr;

    // EPI_QKV: segment (Q/K/V) is block-uniform since 1024/128 = 8 | bn
    const int seg = bn >> 3;
    ushort_t* qkv_out = (EPI == EPI_QKV)
        ? (seg == 0 ? outB : (seg == 1 ? outB2 : outB3)) : outB;
    const float* qkv_bias = (EPI == EPI_QKV)
        ? (seg == 0 ? bias : (seg == 1 ? bias2 : bias3)) : bias;

    #pragma unroll
    for (int i = 0; i < 4; i++) {
        #pragma unroll
        for (int j = 0; j < 4; j++) {
            const int gn = col0 + j * 16;
            const float bsv = (EPI == EPI_QKV) ? qkv_bias[gn & 1023] : bias[gn];
            #pragma unroll
            for (int r = 0; r < 4; r++) {
                const int gm = row0 + i * 16 + r;
                float v = acc[i][j][r] + bsv;
                if (EPI == EPI_QKV) {
                    const size_t oi = (size_t)gm * DMODEL + (gn & 1023);
                    if (seg == 2) {
                        qkv_out[oi] = f2bf(v);               // V
                    } else {
                        float e = v > 0.f ? v + 1.f : __expf(v);   // elu+1
                        if (seg == 1) {                       // K: mask
                            const int b = gm >> 12, s = gm & 4095;
                            if (s >= lens[b]) e = 0.f;
                        }
                        qkv_out[oi] = f2bf(e);
                    }
                } else if (EPI == EPI_RES) {
                    const size_t oi = (size_t)gm * N + gn;
                    outF[oi] = v + res[oi];
                } else {  // EPI_GELU (exact)
                    const size_t oi = (size_t)gm * N + gn;
                    outB[oi] = f2bf(0.5f * v * (1.f + erff(v * 0.70710678118f)));
                }
            }
        }
    }
}

// ---------------------------------------------------------------------------
// Ksum[n, c] = sum_s K[n, s, c]
// ---------------------------------------------------------------------------
__global__ __launch_bounds__(256) void ksum_kernel(const ushort_t* __restrict__ K,
                                                   float* __restrict__ out) {
    const int blk = blockIdx.x;
    const int n = blk >> 4, cg = blk & 15;
    const int tx = threadIdx.x & 63, ty = threadIdx.x >> 6;
    const int col = cg * 64 + tx;
    const ushort_t* p = K + ((size_t)n * SEQ + ty * 1024) * DMODEL + col;
    float a = 0.f;
    for (int s = 0; s < 1024; s++) a += bf2f(p[(size_t)s * DMODEL]);
    __shared__ float red[4][64];
    red[ty][tx] = a;
    __syncthreads();
    if (ty == 0) out[n * DMODEL + col] = red[0][tx] + red[1][tx] + red[2][tx] + red[3][tx];
}

// ---------------------------------------------------------------------------
// KV partials: part[chunk, nh, m, d] = sum_{s in chunk} V[s,m] * K[s,d]
// ---------------------------------------------------------------------------
__global__ __launch_bounds__(256) void kv_part(const ushort_t* __restrict__ K,
                                               const ushort_t* __restrict__ V,
                                               float* __restrict__ part) {
    const int chunk = blockIdx.x, nh = blockIdx.y;
    const int n = nh >> 4, h = nh & 15;
    const int tid = threadIdx.x;
    const int tm = tid >> 4, td = tid & 15;
    __shared__ float Ks[16][68];
    __shared__ float Vs[16][68];
    float acc[4][4] = {};
    const int s0 = chunk * 512;
    for (int sb = 0; sb < 512; sb += 16) {
        __syncthreads();
        for (int idx = tid; idx < 1024; idx += 256) {
            const int r = idx >> 6, c = idx & 63;
            const size_t gpos = ((size_t)(n * SEQ + s0 + sb + r)) * DMODEL + h * HDIM + c;
            Ks[r][c] = bf2f(K[gpos]);
            Vs[r][c] = bf2f(V[gpos]);
        }
        __syncthreads();
        #pragma unroll
        for (int s = 0; s < 16; s++) {
            float kv[4], vv[4];
            #pragma unroll
            for (int j = 0; j < 4; j++) kv[j] = Ks[s][td * 4 + j];
            #pragma unroll
            for (int i = 0; i < 4; i++) vv[i] = Vs[s][tm * 4 + i];
            #pragma unroll
            for (int i = 0; i < 4; i++)
                #pragma unroll
                for (int j = 0; j < 4; j++)
                    acc[i][j] += vv[i] * kv[j];
        }
    }
    float* o = part + ((size_t)chunk * 64 + nh) * 4096;
    #pragma unroll
    for (int i = 0; i < 4; i++)
        #pragma unroll
        for (int j = 0; j < 4; j++)
            o[(tm * 4 + i) * 64 + td * 4 + j] = acc[i][j];
}

__global__ __launch_bounds__(256) void kv_reduce(const float* __restrict__ part,
                                                 float* __restrict__ KV) {
    const int gid = blockIdx.x * 256 + threadIdx.x;
    float a = 0.f;
    #pragma unroll
    for (int c = 0; c < 8; c++) a += part[(size_t)c * (64 * 4096) + gid];
    KV[gid] = a;
}

// ---------------------------------------------------------------------------
// attn[t, h*64+m] = Z * sum_d Q[t,h,d] * KV[nh,m,d],
// Z = 1/(Q . Ksum + eps) computed in-kernel (z_kernel folded in).
// ---------------------------------------------------------------------------
__global__ __launch_bounds__(256) void attn_kernel(const ushort_t* __restrict__ Q,
                                                   const float* __restrict__ KV,
                                                   const float* __restrict__ Ksum,
                                                   ushort_t* __restrict__ out) {
    const int bx = blockIdx.x, nh = blockIdx.y;
    const int n = nh >> 4, h = nh & 15;
    const int tid = threadIdx.x;
    const int ty = tid >> 4, tx = tid & 15;
    __shared__ float KVs[64][65];
    __shared__ float Qs[64][65];
    __shared__ float Zs[64];
    const int t0 = n * SEQ + bx * 64;
    for (int idx = tid; idx < 4096; idx += 256) {
        const int r = idx >> 6, c = idx & 63;
        KVs[r][c] = KV[(size_t)nh * 4096 + idx];
        Qs[r][c] = bf2f(Q[((size_t)(t0 + r)) * DMODEL + h * HDIM + c]);
    }
    __syncthreads();
    if (tid < 64) {
        const float* ks = Ksum + n * DMODEL + h * HDIM;
        float a = 0.f;
        #pragma unroll
        for (int d = 0; d < 64; d++) a += Qs[tid][d] * ks[d];
        Zs[tid] = 1.f / (a + 1e-6f);
    }
    __syncthreads();
    float acc[4][4] = {};
    for (int d = 0; d < 64; d++) {
        float qv[4], kv[4];
        #pragma unroll
        for (int i = 0; i < 4; i++) qv[i] = Qs[ty * 4 + i][d];
        #pragma unroll
        for (int j = 0; j < 4; j++) kv[j] = KVs[tx * 4 + j][d];
        #pragma unroll
        for (int i = 0; i < 4; i++)
            #pragma unroll
            for (int j = 0; j < 4; j++)
                acc[i][j] += qv[i] * kv[j];
    }
    #pragma unroll
    for (int i = 0; i < 4; i++) {
        const int r = ty * 4 + i;
        const float z = Zs[r];
        #pragma unroll
        for (int j = 0; j < 4; j++)
            out[((size_t)(t0 + r)) * DMODEL + h * HDIM + tx * 4 + j] = f2bf(acc[i][j] * z);
    }
}

// ---------------------------------------------------------------------------
// LayerNorm over D=1024 (fp32 in-place ok) + optional bf16 copy
// ---------------------------------------------------------------------------
__global__ __launch_bounds__(256) void ln_kernel(const float* in, float* outF,
                                                 ushort_t* outB,
                                                 const float* __restrict__ g,
                                                 const float* __restrict__ b) {
    const int row = blockIdx.x;
    const int tid = threadIdx.x;
    const float4 v = ((const float4*)(in + (size_t)row * DMODEL))[tid];
    float s = v.x + v.y + v.z + v.w;
    float ss = v.x * v.x + v.y * v.y + v.z * v.z + v.w * v.w;
    #pragma unroll
    for (int off = 32; off; off >>= 1) {
        s += __shfl_down(s, off);
        ss += __shfl_down(ss, off);
    }
    __shared__ float red[8];
    const int lane = tid & 63, w = tid >> 6;
    if (lane == 0) { red[w * 2] = s; red[w * 2 + 1] = ss; }
    __syncthreads();
    s = red[0] + red[2] + red[4] + red[6];
    ss = red[1] + red[3] + red[5] + red[7];
    const float mu = s * (1.f / DMODEL);
    const float var = ss * (1.f / DMODEL) - mu * mu;
    const float rs = rsqrtf(var + 1e-5f);
    const float4 gg = ((const float4*)g)[tid];
    const float4 bb = ((const float4*)b)[tid];
    float4 o;
    o.x = (v.x - mu) * rs * gg.x + bb.x;
    o.y = (v.y - mu) * rs * gg.y + bb.y;
    o.z = (v.z - mu) * rs * gg.z + bb.z;
    o.w = (v.w - mu) * rs * gg.w + bb.w;
    ((float4*)(outF + (size_t)row * DMODEL))[tid] = o;
    if (outB) {
        v4u ob;
        ob[0] = f2bf(o.x); ob[1] = f2bf(o.y); ob[2] = f2bf(o.z); ob[3] = f2bf(o.w);
        *(v4u*)(outB + (size_t)row * DMODEL + tid * 4) = ob;
    }
}

// ---------------------------------------------------------------------------
extern "C" void kernel_launch(void* const* d_in, const int* in_sizes, int n_in,
                              void* d_out, int out_size, void* d_ws, size_t ws_size,
                              hipStream_t stream) {
    const float* src = (const float*)d_in[0];
    const unsigned char* mask = (const unsigned char*)d_in[1];
    const float* Wq = (const float*)d_in[2];
    const float* bq = (const float*)d_in[3];
    const float* Wk = (const float*)d_in[4];
    const float* bk = (const float*)d_in[5];
    const float* Wv = (const float*)d_in[6];
    const float* bv = (const float*)d_in[7];
    const float* Wo = (const float*)d_in[8];
    const float* bo = (const float*)d_in[9];
    const float* W1 = (const float*)d_in[10];
    const float* b1 = (const float*)d_in[11];
    const float* W2 = (const float*)d_in[12];
    const float* b2 = (const float*)d_in[13];
    const float* g1 = (const float*)d_in[14];
    const float* be1 = (const float*)d_in[15];
    const float* g2 = (const float*)d_in[16];
    const float* be2 = (const float*)d_in[17];

    float* xout = (float*)d_out;  // fp32 residual-stream master

    char* ws = (char*)d_ws;
    size_t off = 0;
    auto alloc = [&](size_t bytes) -> void* {
        void* p = (void*)(ws + off);
        off += (bytes + 255) & ~(size_t)255;
        return p;
    };
    const size_t DD = (size_t)DMODEL * DMODEL;
    const size_t FD = (size_t)DFF * DMODEL;
    const size_t MD = (size_t)MTOK * DMODEL;

    ushort_t* wqkv_bf = (ushort_t*)alloc(NLAYER * 3 * DD * 2);  // [L][3][D][D]
    ushort_t* wo_bf = (ushort_t*)alloc(NLAYER * DD * 2);
    ushort_t* w1r = (ushort_t*)alloc(FD * 2);
    ushort_t* w2r = (ushort_t*)alloc(FD * 2);
    ushort_t* xbf = (ushort_t*)alloc(MD * 2);
    ushort_t* Qb = (ushort_t*)alloc(MD * 2);
    ushort_t* Kb = (ushort_t*)alloc(MD * 2);
    ushort_t* Vb = (ushort_t*)alloc(MD * 2);
    (void)alloc(MD * 2);          // hb (=Qb) overlay spans MTOK*DFF bf16
    ushort_t* hb = Qb;
    float* Ksum = (float*)alloc((size_t)NBATCH * DMODEL * 4);
    float* KVp = (float*)alloc((size_t)8 * 64 * 4096 * 4);
    float* KVb = (float*)alloc((size_t)64 * 4096 * 4);
    int* lens = (int*)alloc(256);
    if (off > ws_size) return;

    cvt_qkv<<<dim3((unsigned)((NLAYER * DD) / 1024)), dim3(256), 0, stream>>>(Wq, Wk, Wv, wqkv_bf);
    cvt_bf16<<<dim3((unsigned)((NLAYER * DD) / 1024)), dim3(256), 0, stream>>>(Wo, wo_bf, (int)(NLAYER * DD));
    lens_kernel<<<dim3(1), dim3(256), 0, stream>>>(mask, lens);
    cvt_bf16<<<dim3((unsigned)(MD / 1024)), dim3(256), 0, stream>>>(src, xbf, (int)MD);

    const dim3 blk(256);
    const dim3 gQKV((MTOK / 128) * (3 * DMODEL / 128));  // 3072 blocks
    const dim3 gD((MTOK / 128) * (DMODEL / 128));        // 1024 blocks
    const dim3 gF((MTOK / 128) * (DFF / 128));           // 4096 blocks

    for (int l = 0; l < NLAYER; l++) {
        const ushort_t* wqkvl = wqkv_bf + (size_t)l * 3 * DD;
        const ushort_t* wol = wo_bf + l * DD;
        const float* bql = bq + l * DMODEL;
        const float* bkl = bk + l * DMODEL;
        const float* bvl = bv + l * DMODEL;
        const float* bol = bo + l * DMODEL;
        const float* b1l = b1 + l * DFF;
        const float* b2l = b2 + l * DMODEL;
        const float* g1l = g1 + l * DMODEL;
        const float* be1l = be1 + l * DMODEL;
        const float* g2l = g2 + l * DMODEL;
        const float* be2l = be2 + l * DMODEL;
        const float* resx = (l == 0) ? src : xout;

        // fused Q/K/V projection with feature map + mask
        gemm_bt<EPI_QKV><<<gQKV, blk, 0, stream>>>(xbf, wqkvl, bql, bkl, bvl,
            nullptr, lens, Qb, Kb, Vb, nullptr, MTOK, 3 * DMODEL, DMODEL);

        // linear-attention core
        ksum_kernel<<<dim3(64), blk, 0, stream>>>(Kb, Ksum);
        kv_part<<<dim3(8, 64), blk, 0, stream>>>(Kb, Vb, KVp);
        kv_reduce<<<dim3(64 * 4096 / 256), blk, 0, stream>>>(KVp, KVb);
        attn_kernel<<<dim3(64, 64), blk, 0, stream>>>(Qb, KVb, Ksum, Kb);  // attn -> Kb

        // output projection + residual (fp32), then LN1 + bf16 copy
        gemm_bt<EPI_RES><<<gD, blk, 0, stream>>>(Kb, wol, bol, nullptr, nullptr,
            resx, lens, nullptr, nullptr, nullptr, xout, MTOK, DMODEL, DMODEL);
        ln_kernel<<<dim3(MTOK), blk, 0, stream>>>(xout, xout, xbf, g1l, be1l);

        // FFN
        cvt_bf16<<<dim3((unsigned)(FD / 1024)), blk, 0, stream>>>(W1 + l * FD, w1r, (int)FD);
        gemm_bt<EPI_GELU><<<gF, blk, 0, stream>>>(xbf, w1r, b1l, nullptr, nullptr,
            nullptr, lens, hb, nullptr, nullptr, nullptr, MTOK, DFF, DMODEL);
        cvt_bf16<<<dim3((unsigned)(FD / 1024)), blk, 0, stream>>>(W2 + l * FD, w2r, (int)FD);
        gemm_bt<EPI_RES><<<gD, blk, 0, stream>>>(hb, w2r, b2l, nullptr, nullptr,
            xout, lens, nullptr, nullptr, nullptr, xout, MTOK, DMODEL, DFF);
        ln_kernel<<<dim3(MTOK), blk, 0, stream>>>(xout, xout, (l == NLAYER - 1) ? nullptr : xbf, g2l, be2l);
    }
}

// Round 3
// 3761.837 us; speedup vs baseline: 1.1119x; 1.0574x over previous
//
#include <hip/hip_runtime.h>
#include <cstdint>

typedef unsigned short ushort_t;
typedef short v8s __attribute__((ext_vector_type(8)));
typedef float v4f __attribute__((ext_vector_type(4)));
typedef unsigned short v4u __attribute__((ext_vector_type(4)));

#define DMODEL 1024
#define DFF 4096
#define SEQ 4096
#define NBATCH 4
#define NHEAD 16
#define HDIM 64
#define NLAYER 4
#define MTOK (NBATCH*SEQ)   // 16384

#define EPI_QKV 0
#define EPI_RES 3
#define EPI_GELU 4

__device__ __forceinline__ float bf2f(ushort_t u) {
    unsigned v = ((unsigned)u) << 16; float f; __builtin_memcpy(&f, &v, 4); return f;
}
__device__ __forceinline__ ushort_t f2bf(float f) {
    unsigned u; __builtin_memcpy(&u, &f, 4);
    u = (u + 0x7fffu + ((u >> 16) & 1u)) >> 16;
    return (ushort_t)u;
}

// ---------------------------------------------------------------------------
// fp32 -> bf16 conversion (vectorized, n multiple of 1024)
// ---------------------------------------------------------------------------
__global__ __launch_bounds__(256) void cvt_bf16(const float* __restrict__ in,
                                                ushort_t* __restrict__ out, int n) {
    int i = (blockIdx.x * 256 + threadIdx.x) * 4;
    if (i >= n) return;
    float4 v = *(const float4*)(in + i);
    v4u o;
    o[0] = f2bf(v.x); o[1] = f2bf(v.y); o[2] = f2bf(v.z); o[3] = f2bf(v.w);
    *(v4u*)(out + i) = o;
}

// pack Wq/Wk/Wv (each [L][D][D] fp32) into bf16 [L][3][D][D]
__global__ __launch_bounds__(256) void cvt_qkv(const float* __restrict__ Wq,
                                               const float* __restrict__ Wk,
                                               const float* __restrict__ Wv,
                                               ushort_t* __restrict__ out) {
    const size_t DD = (size_t)DMODEL * DMODEL;
    size_t i = ((size_t)blockIdx.x * 256 + threadIdx.x) * 4;
    int l = (int)(i / DD);
    size_t r = i % DD;
    const float* srcs[3] = { Wq + l * DD + r, Wk + l * DD + r, Wv + l * DD + r };
    #pragma unroll
    for (int s = 0; s < 3; s++) {
        float4 v = *(const float4*)srcs[s];
        v4u o;
        o[0] = f2bf(v.x); o[1] = f2bf(v.y); o[2] = f2bf(v.z); o[3] = f2bf(v.w);
        *(v4u*)(out + ((size_t)l * 3 + s) * DD + r) = o;
    }
}

// ---------------------------------------------------------------------------
__global__ __launch_bounds__(256) void lens_kernel(const unsigned char* __restrict__ mask,
                                                   int* __restrict__ lens) {
    int lane = threadIdx.x & 63, w = threadIdx.x >> 6;
    int cnt = 0;
    for (int i = lane; i < SEQ; i += 64) cnt += (mask[w * SEQ + i] != 0) ? 1 : 0;
    #pragma unroll
    for (int off = 32; off; off >>= 1) cnt += __shfl_down(cnt, off);
    if (lane == 0) lens[w] = SEQ - cnt;
}

// ---------------------------------------------------------------------------
// GEMM: C[M,N] = A[M,K] @ B[N,K]^T, bf16 in, fp32 acc, fused epilogues.
// 128x128 tile, 4 waves of 64x64, BK=64 (32 KB LDS), global_load_lds w=16.
// XCD-aware remap: same-bm blocks share an XCD (A-tile L2 reuse).
// 8-chunk XOR swizzle (chunk ^= row&7) -> conflict-free 64-ushort LDS rows.
// ---------------------------------------------------------------------------
template <int EPI>
__global__ __launch_bounds__(256) void gemm_bt(
    const ushort_t* __restrict__ A, const ushort_t* __restrict__ B,
    const float* __restrict__ bias, const float* __restrict__ bias2,
    const float* __restrict__ bias3, const float* res,
    const int* __restrict__ lens,
    ushort_t* __restrict__ outB, ushort_t* __restrict__ outB2,
    ushort_t* __restrict__ outB3, float* outF,
    int M, int N, int K)
{
    __shared__ __align__(16) ushort_t As[128 * 64];
    __shared__ __align__(16) ushort_t Bs[128 * 64];

    const int tid = threadIdx.x;
    const int lane = tid & 63;
    const int wave = tid >> 6;
    const int nb = N >> 7;
    // XCD-aware remap (dispatch round-robins XCD = blockIdx.x % 8)
    const int xcd = blockIdx.x & 7;
    const int q = blockIdx.x >> 3;
    const int bm = (q / nb) * 8 + xcd;   // M/128 = 128, divisible by 8
    const int bn = q % nb;
    const int wm = (wave >> 1) * 64;
    const int wn = (wave & 1) * 64;
    const int lr = lane & 15;
    const int lq = lane >> 4;  // 0..3

    v4f acc[4][4];
    #pragma unroll
    for (int i = 0; i < 4; i++)
        #pragma unroll
        for (int j = 0; j < 4; j++) acc[i][j] = (v4f)0.f;

    // staging: inst i covers rows i*32 + (tid>>3); 8 chunks (16B) per 64-elem row,
    // source chunk XOR-swizzled so LDS slot s of row r holds global chunk s^(r&7).
    const int srow = tid >> 3;               // 0..31
    const int schunk = (tid & 7) ^ (srow & 7);
    const ushort_t* Ag = A + (size_t)(bm * 128 + srow) * K + schunk * 8;
    const ushort_t* Bg = B + (size_t)(bn * 128 + srow) * K + schunk * 8;
    ushort_t* Asp = As + tid * 8;
    ushort_t* Bsp = Bs + tid * 8;
    const size_t rstep = (size_t)32 * K;     // 32 rows per staging instruction

    // fragment LDS ushort offsets (k-invariant, read-side XOR)
    int a_off[2][4], b_off[2][4];
    #pragma unroll
    for (int h = 0; h < 2; h++)
        #pragma unroll
        for (int i = 0; i < 4; i++) {
            const int ra = wm + i * 16 + lr;
            a_off[h][i] = ra * 64 + (((h * 4 + lq) ^ (ra & 7)) * 8);
            const int rb = wn + i * 16 + lr;
            b_off[h][i] = rb * 64 + (((h * 4 + lq) ^ (rb & 7)) * 8);
        }

    for (int k0 = 0; k0 < K; k0 += 64) {
        #pragma unroll
        for (int i = 0; i < 4; i++)
            __builtin_amdgcn_global_load_lds((const void*)(Ag + i * rstep + k0),
                                             (void*)(Asp + i * 2048), 16, 0, 0);
        #pragma unroll
        for (int i = 0; i < 4; i++)
            __builtin_amdgcn_global_load_lds((const void*)(Bg + i * rstep + k0),
                                             (void*)(Bsp + i * 2048), 16, 0, 0);
        __syncthreads();

        #pragma unroll
        for (int h = 0; h < 2; h++) {
            v8s af[4], bfr[4];
            #pragma unroll
            for (int i = 0; i < 4; i++) af[i] = *(const v8s*)&As[a_off[h][i]];
            #pragma unroll
            for (int j = 0; j < 4; j++) bfr[j] = *(const v8s*)&Bs[b_off[h][j]];
            #pragma unroll
            for (int i = 0; i < 4; i++)
                #pragma unroll
                for (int j = 0; j < 4; j++)
                    acc[i][j] = __builtin_amdgcn_mfma_f32_16x16x32_bf16(af[i], bfr[j], acc[i][j], 0, 0, 0);
        }
        __syncthreads();
    }

    // epilogue: C/D layout col = lane&15, row = (lane>>4)*4 + reg
    const int row0 = bm * 128 + wm + lq * 4;
    const int col0 = bn * 128 + wn + lr;

    const int seg = bn >> 3;   // EPI_QKV: block-uniform Q/K/V segment
    ushort_t* qkv_out = (EPI == EPI_QKV)
        ? (seg == 0 ? outB : (seg == 1 ? outB2 : outB3)) : outB;
    const float* qkv_bias = (EPI == EPI_QKV)
        ? (seg == 0 ? bias : (seg == 1 ? bias2 : bias3)) : bias;

    #pragma unroll
    for (int i = 0; i < 4; i++) {
        #pragma unroll
        for (int j = 0; j < 4; j++) {
            const int gn = col0 + j * 16;
            const float bsv = (EPI == EPI_QKV) ? qkv_bias[gn & 1023] : bias[gn];
            #pragma unroll
            for (int r = 0; r < 4; r++) {
                const int gm = row0 + i * 16 + r;
                float v = acc[i][j][r] + bsv;
                if (EPI == EPI_QKV) {
                    const size_t oi = (size_t)gm * DMODEL + (gn & 1023);
                    if (seg == 2) {
                        qkv_out[oi] = f2bf(v);                    // V
                    } else {
                        float e = v > 0.f ? v + 1.f : __expf(v);  // elu+1
                        if (seg == 1) {                           // K: mask
                            const int b = gm >> 12, s = gm & 4095;
                            if (s >= lens[b]) e = 0.f;
                        }
                        qkv_out[oi] = f2bf(e);
                    }
                } else if (EPI == EPI_RES) {
                    const size_t oi = (size_t)gm * N + gn;
                    outF[oi] = v + res[oi];
                } else {  // EPI_GELU (exact)
                    const size_t oi = (size_t)gm * N + gn;
                    outB[oi] = f2bf(0.5f * v * (1.f + erff(v * 0.70710678118f)));
                }
            }
        }
    }
}

// ---------------------------------------------------------------------------
__global__ __launch_bounds__(256) void ksum_kernel(const ushort_t* __restrict__ K,
                                                   float* __restrict__ out) {
    const int blk = blockIdx.x;
    const int n = blk >> 4, cg = blk & 15;
    const int tx = threadIdx.x & 63, ty = threadIdx.x >> 6;
    const int col = cg * 64 + tx;
    const ushort_t* p = K + ((size_t)n * SEQ + ty * 1024) * DMODEL + col;
    float a = 0.f;
    for (int s = 0; s < 1024; s++) a += bf2f(p[(size_t)s * DMODEL]);
    __shared__ float red[4][64];
    red[ty][tx] = a;
    __syncthreads();
    if (ty == 0) out[n * DMODEL + col] = red[0][tx] + red[1][tx] + red[2][tx] + red[3][tx];
}

// ---------------------------------------------------------------------------
__global__ __launch_bounds__(256) void kv_part(const ushort_t* __restrict__ K,
                                               const ushort_t* __restrict__ V,
                                               float* __restrict__ part) {
    const int chunk = blockIdx.x, nh = blockIdx.y;
    const int n = nh >> 4, h = nh & 15;
    const int tid = threadIdx.x;
    const int tm = tid >> 4, td = tid & 15;
    __shared__ float Ks[16][68];
    __shared__ float Vs[16][68];
    float acc[4][4] = {};
    const int s0 = chunk * 512;
    for (int sb = 0; sb < 512; sb += 16) {
        __syncthreads();
        for (int idx = tid; idx < 1024; idx += 256) {
            const int r = idx >> 6, c = idx & 63;
            const size_t gpos = ((size_t)(n * SEQ + s0 + sb + r)) * DMODEL + h * HDIM + c;
            Ks[r][c] = bf2f(K[gpos]);
            Vs[r][c] = bf2f(V[gpos]);
        }
        __syncthreads();
        #pragma unroll
        for (int s = 0; s < 16; s++) {
            float kv[4], vv[4];
            #pragma unroll
            for (int j = 0; j < 4; j++) kv[j] = Ks[s][td * 4 + j];
            #pragma unroll
            for (int i = 0; i < 4; i++) vv[i] = Vs[s][tm * 4 + i];
            #pragma unroll
            for (int i = 0; i < 4; i++)
                #pragma unroll
                for (int j = 0; j < 4; j++)
                    acc[i][j] += vv[i] * kv[j];
        }
    }
    float* o = part + ((size_t)chunk * 64 + nh) * 4096;
    #pragma unroll
    for (int i = 0; i < 4; i++)
        #pragma unroll
        for (int j = 0; j < 4; j++)
            o[(tm * 4 + i) * 64 + td * 4 + j] = acc[i][j];
}

__global__ __launch_bounds__(256) void kv_reduce(const float* __restrict__ part,
                                                 float* __restrict__ KV) {
    const int gid = blockIdx.x * 256 + threadIdx.x;
    float a = 0.f;
    #pragma unroll
    for (int c = 0; c < 8; c++) a += part[(size_t)c * (64 * 4096) + gid];
    KV[gid] = a;
}

// ---------------------------------------------------------------------------
__global__ __launch_bounds__(256) void attn_kernel(const ushort_t* __restrict__ Q,
                                                   const float* __restrict__ KV,
                                                   const float* __restrict__ Ksum,
                                                   ushort_t* __restrict__ out) {
    const int bx = blockIdx.x, nh = blockIdx.y;
    const int n = nh >> 4, h = nh & 15;
    const int tid = threadIdx.x;
    const int ty = tid >> 4, tx = tid & 15;
    __shared__ float KVs[64][65];
    __shared__ float Qs[64][65];
    __shared__ float Zs[64];
    const int t0 = n * SEQ + bx * 64;
    for (int idx = tid; idx < 4096; idx += 256) {
        const int r = idx >> 6, c = idx & 63;
        KVs[r][c] = KV[(size_t)nh * 4096 + idx];
        Qs[r][c] = bf2f(Q[((size_t)(t0 + r)) * DMODEL + h * HDIM + c]);
    }
    __syncthreads();
    if (tid < 64) {
        const float* ks = Ksum + n * DMODEL + h * HDIM;
        float a = 0.f;
        #pragma unroll
        for (int d = 0; d < 64; d++) a += Qs[tid][d] * ks[d];
        Zs[tid] = 1.f / (a + 1e-6f);
    }
    __syncthreads();
    float acc[4][4] = {};
    for (int d = 0; d < 64; d++) {
        float qv[4], kv[4];
        #pragma unroll
        for (int i = 0; i < 4; i++) qv[i] = Qs[ty * 4 + i][d];
        #pragma unroll
        for (int j = 0; j < 4; j++) kv[j] = KVs[tx * 4 + j][d];
        #pragma unroll
        for (int i = 0; i < 4; i++)
            #pragma unroll
            for (int j = 0; j < 4; j++)
                acc[i][j] += qv[i] * kv[j];
    }
    #pragma unroll
    for (int i = 0; i < 4; i++) {
        const int r = ty * 4 + i;
        const float z = Zs[r];
        #pragma unroll
        for (int j = 0; j < 4; j++)
            out[((size_t)(t0 + r)) * DMODEL + h * HDIM + tx * 4 + j] = f2bf(acc[i][j] * z);
    }
}

// ---------------------------------------------------------------------------
__global__ __launch_bounds__(256) void ln_kernel(const float* in, float* outF,
                                                 ushort_t* outB,
                                                 const float* __restrict__ g,
                                                 const float* __restrict__ b) {
    const int row = blockIdx.x;
    const int tid = threadIdx.x;
    const float4 v = ((const float4*)(in + (size_t)row * DMODEL))[tid];
    float s = v.x + v.y + v.z + v.w;
    float ss = v.x * v.x + v.y * v.y + v.z * v.z + v.w * v.w;
    #pragma unroll
    for (int off = 32; off; off >>= 1) {
        s += __shfl_down(s, off);
        ss += __shfl_down(ss, off);
    }
    __shared__ float red[8];
    const int lane = tid & 63, w = tid >> 6;
    if (lane == 0) { red[w * 2] = s; red[w * 2 + 1] = ss; }
    __syncthreads();
    s = red[0] + red[2] + red[4] + red[6];
    ss = red[1] + red[3] + red[5] + red[7];
    const float mu = s * (1.f / DMODEL);
    const float var = ss * (1.f / DMODEL) - mu * mu;
    const float rs = rsqrtf(var + 1e-5f);
    const float4 gg = ((const float4*)g)[tid];
    const float4 bb = ((const float4*)b)[tid];
    float4 o;
    o.x = (v.x - mu) * rs * gg.x + bb.x;
    o.y = (v.y - mu) * rs * gg.y + bb.y;
    o.z = (v.z - mu) * rs * gg.z + bb.z;
    o.w = (v.w - mu) * rs * gg.w + bb.w;
    ((float4*)(outF + (size_t)row * DMODEL))[tid] = o;
    if (outB) {
        v4u ob;
        ob[0] = f2bf(o.x); ob[1] = f2bf(o.y); ob[2] = f2bf(o.z); ob[3] = f2bf(o.w);
        *(v4u*)(outB + (size_t)row * DMODEL + tid * 4) = ob;
    }
}

// ---------------------------------------------------------------------------
extern "C" void kernel_launch(void* const* d_in, const int* in_sizes, int n_in,
                              void* d_out, int out_size, void* d_ws, size_t ws_size,
                              hipStream_t stream) {
    const float* src = (const float*)d_in[0];
    const unsigned char* mask = (const unsigned char*)d_in[1];
    const float* Wq = (const float*)d_in[2];
    const float* bq = (const float*)d_in[3];
    const float* Wk = (const float*)d_in[4];
    const float* bk = (const float*)d_in[5];
    const float* Wv = (const float*)d_in[6];
    const float* bv = (const float*)d_in[7];
    const float* Wo = (const float*)d_in[8];
    const float* bo = (const float*)d_in[9];
    const float* W1 = (const float*)d_in[10];
    const float* b1 = (const float*)d_in[11];
    const float* W2 = (const float*)d_in[12];
    const float* b2 = (const float*)d_in[13];
    const float* g1 = (const float*)d_in[14];
    const float* be1 = (const float*)d_in[15];
    const float* g2 = (const float*)d_in[16];
    const float* be2 = (const float*)d_in[17];

    float* xout = (float*)d_out;  // fp32 residual-stream master

    char* ws = (char*)d_ws;
    size_t off = 0;
    auto alloc = [&](size_t bytes) -> void* {
        void* p = (void*)(ws + off);
        off += (bytes + 255) & ~(size_t)255;
        return p;
    };
    const size_t DD = (size_t)DMODEL * DMODEL;
    const size_t FD = (size_t)DFF * DMODEL;
    const size_t MD = (size_t)MTOK * DMODEL;

    ushort_t* wqkv_bf = (ushort_t*)alloc(NLAYER * 3 * DD * 2);  // [L][3][D][D]
    ushort_t* wo_bf = (ushort_t*)alloc(NLAYER * DD * 2);
    ushort_t* w1r = (ushort_t*)alloc(FD * 2);
    ushort_t* w2r = (ushort_t*)alloc(FD * 2);
    ushort_t* xbf = (ushort_t*)alloc(MD * 2);
    ushort_t* Qb = (ushort_t*)alloc(MD * 2);
    ushort_t* Kb = (ushort_t*)alloc(MD * 2);
    ushort_t* Vb = (ushort_t*)alloc(MD * 2);
    (void)alloc(MD * 2);          // hb (=Qb) overlay spans MTOK*DFF bf16
    ushort_t* hb = Qb;
    float* Ksum = (float*)alloc((size_t)NBATCH * DMODEL * 4);
    float* KVp = (float*)alloc((size_t)8 * 64 * 4096 * 4);
    float* KVb = (float*)alloc((size_t)64 * 4096 * 4);
    int* lens = (int*)alloc(256);
    if (off > ws_size) return;

    cvt_qkv<<<dim3((unsigned)((NLAYER * DD) / 1024)), dim3(256), 0, stream>>>(Wq, Wk, Wv, wqkv_bf);
    cvt_bf16<<<dim3((unsigned)((NLAYER * DD) / 1024)), dim3(256), 0, stream>>>(Wo, wo_bf, (int)(NLAYER * DD));
    lens_kernel<<<dim3(1), dim3(256), 0, stream>>>(mask, lens);
    cvt_bf16<<<dim3((unsigned)(MD / 1024)), dim3(256), 0, stream>>>(src, xbf, (int)MD);

    const dim3 blk(256);
    const dim3 gQKV((MTOK / 128) * (3 * DMODEL / 128));  // 3072 blocks
    const dim3 gD((MTOK / 128) * (DMODEL / 128));        // 1024 blocks
    const dim3 gF((MTOK / 128) * (DFF / 128));           // 4096 blocks

    for (int l = 0; l < NLAYER; l++) {
        const ushort_t* wqkvl = wqkv_bf + (size_t)l * 3 * DD;
        const ushort_t* wol = wo_bf + l * DD;
        const float* bql = bq + l * DMODEL;
        const float* bkl = bk + l * DMODEL;
        const float* bvl = bv + l * DMODEL;
        const float* bol = bo + l * DMODEL;
        const float* b1l = b1 + l * DFF;
        const float* b2l = b2 + l * DMODEL;
        const float* g1l = g1 + l * DMODEL;
        const float* be1l = be1 + l * DMODEL;
        const float* g2l = g2 + l * DMODEL;
        const float* be2l = be2 + l * DMODEL;
        const float* resx = (l == 0) ? src : xout;

        // fused Q/K/V projection with feature map + mask
        gemm_bt<EPI_QKV><<<gQKV, blk, 0, stream>>>(xbf, wqkvl, bql, bkl, bvl,
            nullptr, lens, Qb, Kb, Vb, nullptr, MTOK, 3 * DMODEL, DMODEL);

        // linear-attention core
        ksum_kernel<<<dim3(64), blk, 0, stream>>>(Kb, Ksum);
        kv_part<<<dim3(8, 64), blk, 0, stream>>>(Kb, Vb, KVp);
        kv_reduce<<<dim3(64 * 4096 / 256), blk, 0, stream>>>(KVp, KVb);
        attn_kernel<<<dim3(64, 64), blk, 0, stream>>>(Qb, KVb, Ksum, Kb);  // attn -> Kb

        // output projection + residual (fp32), then LN1 + bf16 copy
        gemm_bt<EPI_RES><<<gD, blk, 0, stream>>>(Kb, wol, bol, nullptr, nullptr,
            resx, lens, nullptr, nullptr, nullptr, xout, MTOK, DMODEL, DMODEL);
        ln_kernel<<<dim3(MTOK), blk, 0, stream>>>(xout, xout, xbf, g1l, be1l);

        // FFN
        cvt_bf16<<<dim3((unsigned)(FD / 1024)), blk, 0, stream>>>(W1 + l * FD, w1r, (int)FD);
        gemm_bt<EPI_GELU><<<gF, blk, 0, stream>>>(xbf, w1r, b1l, nullptr, nullptr,
            nullptr, lens, hb, nullptr, nullptr, nullptr, MTOK, DFF, DMODEL);
        cvt_bf16<<<dim3((unsigned)(FD / 1024)), blk, 0, stream>>>(W2 + l * FD, w2r, (int)FD);
        gemm_bt<EPI_RES><<<gD, blk, 0, stream>>>(hb, w2r, b2l, nullptr, nullptr,
            xout, lens, nullptr, nullptr, nullptr, xout, MTOK, DMODEL, DFF);
        ln_kernel<<<dim3(MTOK), blk, 0, stream>>>(xout, xout, (l == NLAYER - 1) ? nullptr : xbf, g2l, be2l);
    }
}

// Round 4
// 3662.194 us; speedup vs baseline: 1.1422x; 1.0272x over previous
//
#include <hip/hip_runtime.h>
#include <cstdint>

typedef unsigned short ushort_t;
typedef short v8s __attribute__((ext_vector_type(8)));
typedef float v4f __attribute__((ext_vector_type(4)));
typedef unsigned short v4u __attribute__((ext_vector_type(4)));

#define DMODEL 1024
#define DFF 4096
#define SEQ 4096
#define NBATCH 4
#define NHEAD 16
#define HDIM 64
#define NLAYER 4
#define MTOK (NBATCH*SEQ)   // 16384

#define EPI_QKV 0
#define EPI_RES 3
#define EPI_GELU 4

__device__ __forceinline__ float bf2f(ushort_t u) {
    unsigned v = ((unsigned)u) << 16; float f; __builtin_memcpy(&f, &v, 4); return f;
}
__device__ __forceinline__ ushort_t f2bf(float f) {
    unsigned u; __builtin_memcpy(&u, &f, 4);
    u = (u + 0x7fffu + ((u >> 16) & 1u)) >> 16;
    return (ushort_t)u;
}

// exact-form GELU with A&S 7.1.26 erf approximation (|err| <= 1.5e-7).
// ~14 VALU ops (1 v_exp, 1 v_rcp) vs libm erff's ~40+.
__device__ __forceinline__ float gelu_f(float x) {
    const float y = x * 0.70710678118f;
    const float ay = fabsf(y);
    const float t = __builtin_amdgcn_rcpf(1.f + 0.3275911f * ay);
    const float p = t * (0.254829592f + t * (-0.284496736f + t * (1.421413741f +
                    t * (-1.453152027f + t * 1.061405429f))));
    const float e = __expf(-y * y);
    float er = 1.f - p * e;
    er = (y < 0.f) ? -er : er;
    return 0.5f * x * (1.f + er);
}

// ---------------------------------------------------------------------------
// fp32 -> bf16 conversion (vectorized, n multiple of 1024)
// ---------------------------------------------------------------------------
__global__ __launch_bounds__(256) void cvt_bf16(const float* __restrict__ in,
                                                ushort_t* __restrict__ out, int n) {
    int i = (blockIdx.x * 256 + threadIdx.x) * 4;
    if (i >= n) return;
    float4 v = *(const float4*)(in + i);
    v4u o;
    o[0] = f2bf(v.x); o[1] = f2bf(v.y); o[2] = f2bf(v.z); o[3] = f2bf(v.w);
    *(v4u*)(out + i) = o;
}

// pack Wq/Wk/Wv (each [L][D][D] fp32) into bf16 [L][3][D][D]
__global__ __launch_bounds__(256) void cvt_qkv(const float* __restrict__ Wq,
                                               const float* __restrict__ Wk,
                                               const float* __restrict__ Wv,
                                               ushort_t* __restrict__ out) {
    const size_t DD = (size_t)DMODEL * DMODEL;
    size_t i = ((size_t)blockIdx.x * 256 + threadIdx.x) * 4;
    int l = (int)(i / DD);
    size_t r = i % DD;
    const float* srcs[3] = { Wq + l * DD + r, Wk + l * DD + r, Wv + l * DD + r };
    #pragma unroll
    for (int s = 0; s < 3; s++) {
        float4 v = *(const float4*)srcs[s];
        v4u o;
        o[0] = f2bf(v.x); o[1] = f2bf(v.y); o[2] = f2bf(v.z); o[3] = f2bf(v.w);
        *(v4u*)(out + ((size_t)l * 3 + s) * DD + r) = o;
    }
}

// ---------------------------------------------------------------------------
__global__ __launch_bounds__(256) void lens_kernel(const unsigned char* __restrict__ mask,
                                                   int* __restrict__ lens) {
    int lane = threadIdx.x & 63, w = threadIdx.x >> 6;
    int cnt = 0;
    for (int i = lane; i < SEQ; i += 64) cnt += (mask[w * SEQ + i] != 0) ? 1 : 0;
    #pragma unroll
    for (int off = 32; off; off >>= 1) cnt += __shfl_down(cnt, off);
    if (lane == 0) lens[w] = SEQ - cnt;
}

// ---------------------------------------------------------------------------
// GEMM: C[M,N] = A[M,K] @ B[N,K]^T, bf16 in, fp32 acc, fused epilogues.
// 128x128 tile, 4 waves of 64x64, BK=64 (32 KB LDS), global_load_lds w=16.
// XCD-aware remap: same-bm blocks share an XCD (A-tile L2 reuse).
// 8-chunk XOR swizzle (chunk ^= row&7) -> conflict-free 64-ushort LDS rows.
// EPI_GELU uses nontemporal stores: the 134 MB hb stream otherwise thrashes
// L3 and evicts the B operand between reuses (R3: FETCH 280 MB vs 42 ideal).
// ---------------------------------------------------------------------------
template <int EPI>
__global__ __launch_bounds__(256) void gemm_bt(
    const ushort_t* __restrict__ A, const ushort_t* __restrict__ B,
    const float* __restrict__ bias, const float* __restrict__ bias2,
    const float* __restrict__ bias3, const float* res,
    const int* __restrict__ lens,
    ushort_t* __restrict__ outB, ushort_t* __restrict__ outB2,
    ushort_t* __restrict__ outB3, float* outF,
    int M, int N, int K)
{
    __shared__ __align__(16) ushort_t As[128 * 64];
    __shared__ __align__(16) ushort_t Bs[128 * 64];

    const int tid = threadIdx.x;
    const int lane = tid & 63;
    const int wave = tid >> 6;
    const int nb = N >> 7;
    // XCD-aware remap (dispatch round-robins XCD = blockIdx.x % 8)
    const int xcd = blockIdx.x & 7;
    const int q = blockIdx.x >> 3;
    const int bm = (q / nb) * 8 + xcd;   // M/128 = 128, divisible by 8
    const int bn = q % nb;
    const int wm = (wave >> 1) * 64;
    const int wn = (wave & 1) * 64;
    const int lr = lane & 15;
    const int lq = lane >> 4;  // 0..3

    v4f acc[4][4];
    #pragma unroll
    for (int i = 0; i < 4; i++)
        #pragma unroll
        for (int j = 0; j < 4; j++) acc[i][j] = (v4f)0.f;

    // staging: inst i covers rows i*32 + (tid>>3); 8 chunks (16B) per 64-elem row,
    // source chunk XOR-swizzled so LDS slot s of row r holds global chunk s^(r&7).
    const int srow = tid >> 3;               // 0..31
    const int schunk = (tid & 7) ^ (srow & 7);
    const ushort_t* Ag = A + (size_t)(bm * 128 + srow) * K + schunk * 8;
    const ushort_t* Bg = B + (size_t)(bn * 128 + srow) * K + schunk * 8;
    ushort_t* Asp = As + tid * 8;
    ushort_t* Bsp = Bs + tid * 8;
    const size_t rstep = (size_t)32 * K;     // 32 rows per staging instruction

    // fragment LDS ushort offsets (k-invariant, read-side XOR)
    int a_off[2][4], b_off[2][4];
    #pragma unroll
    for (int h = 0; h < 2; h++)
        #pragma unroll
        for (int i = 0; i < 4; i++) {
            const int ra = wm + i * 16 + lr;
            a_off[h][i] = ra * 64 + (((h * 4 + lq) ^ (ra & 7)) * 8);
            const int rb = wn + i * 16 + lr;
            b_off[h][i] = rb * 64 + (((h * 4 + lq) ^ (rb & 7)) * 8);
        }

    for (int k0 = 0; k0 < K; k0 += 64) {
        #pragma unroll
        for (int i = 0; i < 4; i++)
            __builtin_amdgcn_global_load_lds((const void*)(Ag + i * rstep + k0),
                                             (void*)(Asp + i * 2048), 16, 0, 0);
        #pragma unroll
        for (int i = 0; i < 4; i++)
            __builtin_amdgcn_global_load_lds((const void*)(Bg + i * rstep + k0),
                                             (void*)(Bsp + i * 2048), 16, 0, 0);
        __syncthreads();

        #pragma unroll
        for (int h = 0; h < 2; h++) {
            v8s af[4], bfr[4];
            #pragma unroll
            for (int i = 0; i < 4; i++) af[i] = *(const v8s*)&As[a_off[h][i]];
            #pragma unroll
            for (int j = 0; j < 4; j++) bfr[j] = *(const v8s*)&Bs[b_off[h][j]];
            #pragma unroll
            for (int i = 0; i < 4; i++)
                #pragma unroll
                for (int j = 0; j < 4; j++)
                    acc[i][j] = __builtin_amdgcn_mfma_f32_16x16x32_bf16(af[i], bfr[j], acc[i][j], 0, 0, 0);
        }
        __syncthreads();
    }

    // epilogue: C/D layout col = lane&15, row = (lane>>4)*4 + reg
    const int row0 = bm * 128 + wm + lq * 4;
    const int col0 = bn * 128 + wn + lr;

    const int seg = bn >> 3;   // EPI_QKV: block-uniform Q/K/V segment
    ushort_t* qkv_out = (EPI == EPI_QKV)
        ? (seg == 0 ? outB : (seg == 1 ? outB2 : outB3)) : outB;
    const float* qkv_bias = (EPI == EPI_QKV)
        ? (seg == 0 ? bias : (seg == 1 ? bias2 : bias3)) : bias;
    // batch index is block-uniform (128 | 4096): hoist the mask length load
    const int blen = (EPI == EPI_QKV) ? lens[bm >> 5] : 0;

    #pragma unroll
    for (int i = 0; i < 4; i++) {
        #pragma unroll
        for (int j = 0; j < 4; j++) {
            const int gn = col0 + j * 16;
            const float bsv = (EPI == EPI_QKV) ? qkv_bias[gn & 1023] : bias[gn];
            #pragma unroll
            for (int r = 0; r < 4; r++) {
                const int gm = row0 + i * 16 + r;
                float v = acc[i][j][r] + bsv;
                if (EPI == EPI_QKV) {
                    const size_t oi = (size_t)gm * DMODEL + (gn & 1023);
                    if (seg == 2) {
                        qkv_out[oi] = f2bf(v);                    // V
                    } else {
                        float e = v > 0.f ? v + 1.f : __expf(v);  // elu+1
                        if (seg == 1 && (gm & 4095) >= blen) e = 0.f;  // K mask
                        qkv_out[oi] = f2bf(e);
                    }
                } else if (EPI == EPI_RES) {
                    const size_t oi = (size_t)gm * N + gn;
                    outF[oi] = v + res[oi];
                } else {  // EPI_GELU: cheap erf + nontemporal (cache-bypass) store
                    const size_t oi = (size_t)gm * N + gn;
                    __builtin_nontemporal_store(f2bf(gelu_f(v)), &outB[oi]);
                }
            }
        }
    }
}

// ---------------------------------------------------------------------------
__global__ __launch_bounds__(256) void ksum_kernel(const ushort_t* __restrict__ K,
                                                   float* __restrict__ out) {
    const int blk = blockIdx.x;
    const int n = blk >> 4, cg = blk & 15;
    const int tx = threadIdx.x & 63, ty = threadIdx.x >> 6;
    const int col = cg * 64 + tx;
    const ushort_t* p = K + ((size_t)n * SEQ + ty * 1024) * DMODEL + col;
    float a = 0.f;
    for (int s = 0; s < 1024; s++) a += bf2f(p[(size_t)s * DMODEL]);
    __shared__ float red[4][64];
    red[ty][tx] = a;
    __syncthreads();
    if (ty == 0) out[n * DMODEL + col] = red[0][tx] + red[1][tx] + red[2][tx] + red[3][tx];
}

// ---------------------------------------------------------------------------
__global__ __launch_bounds__(256) void kv_part(const ushort_t* __restrict__ K,
                                               const ushort_t* __restrict__ V,
                                               float* __restrict__ part) {
    const int chunk = blockIdx.x, nh = blockIdx.y;
    const int n = nh >> 4, h = nh & 15;
    const int tid = threadIdx.x;
    const int tm = tid >> 4, td = tid & 15;
    __shared__ float Ks[16][68];
    __shared__ float Vs[16][68];
    float acc[4][4] = {};
    const int s0 = chunk * 512;
    for (int sb = 0; sb < 512; sb += 16) {
        __syncthreads();
        for (int idx = tid; idx < 1024; idx += 256) {
            const int r = idx >> 6, c = idx & 63;
            const size_t gpos = ((size_t)(n * SEQ + s0 + sb + r)) * DMODEL + h * HDIM + c;
            Ks[r][c] = bf2f(K[gpos]);
            Vs[r][c] = bf2f(V[gpos]);
        }
        __syncthreads();
        #pragma unroll
        for (int s = 0; s < 16; s++) {
            float kv[4], vv[4];
            #pragma unroll
            for (int j = 0; j < 4; j++) kv[j] = Ks[s][td * 4 + j];
            #pragma unroll
            for (int i = 0; i < 4; i++) vv[i] = Vs[s][tm * 4 + i];
            #pragma unroll
            for (int i = 0; i < 4; i++)
                #pragma unroll
                for (int j = 0; j < 4; j++)
                    acc[i][j] += vv[i] * kv[j];
        }
    }
    float* o = part + ((size_t)chunk * 64 + nh) * 4096;
    #pragma unroll
    for (int i = 0; i < 4; i++)
        #pragma unroll
        for (int j = 0; j < 4; j++)
            o[(tm * 4 + i) * 64 + td * 4 + j] = acc[i][j];
}

__global__ __launch_bounds__(256) void kv_reduce(const float* __restrict__ part,
                                                 float* __restrict__ KV) {
    const int gid = blockIdx.x * 256 + threadIdx.x;
    float a = 0.f;
    #pragma unroll
    for (int c = 0; c < 8; c++) a += part[(size_t)c * (64 * 4096) + gid];
    KV[gid] = a;
}

// ---------------------------------------------------------------------------
__global__ __launch_bounds__(256) void attn_kernel(const ushort_t* __restrict__ Q,
                                                   const float* __restrict__ KV,
                                                   const float* __restrict__ Ksum,
                                                   ushort_t* __restrict__ out) {
    const int bx = blockIdx.x, nh = blockIdx.y;
    const int n = nh >> 4, h = nh & 15;
    const int tid = threadIdx.x;
    const int ty = tid >> 4, tx = tid & 15;
    __shared__ float KVs[64][65];
    __shared__ float Qs[64][65];
    __shared__ float Zs[64];
    const int t0 = n * SEQ + bx * 64;
    for (int idx = tid; idx < 4096; idx += 256) {
        const int r = idx >> 6, c = idx & 63;
        KVs[r][c] = KV[(size_t)nh * 4096 + idx];
        Qs[r][c] = bf2f(Q[((size_t)(t0 + r)) * DMODEL + h * HDIM + c]);
    }
    __syncthreads();
    if (tid < 64) {
        const float* ks = Ksum + n * DMODEL + h * HDIM;
        float a = 0.f;
        #pragma unroll
        for (int d = 0; d < 64; d++) a += Qs[tid][d] * ks[d];
        Zs[tid] = 1.f / (a + 1e-6f);
    }
    __syncthreads();
    float acc[4][4] = {};
    for (int d = 0; d < 64; d++) {
        float qv[4], kv[4];
        #pragma unroll
        for (int i = 0; i < 4; i++) qv[i] = Qs[ty * 4 + i][d];
        #pragma unroll
        for (int j = 0; j < 4; j++) kv[j] = KVs[tx * 4 + j][d];
        #pragma unroll
        for (int i = 0; i < 4; i++)
            #pragma unroll
            for (int j = 0; j < 4; j++)
                acc[i][j] += qv[i] * kv[j];
    }
    #pragma unroll
    for (int i = 0; i < 4; i++) {
        const int r = ty * 4 + i;
        const float z = Zs[r];
        v4u o;
        #pragma unroll
        for (int j = 0; j < 4; j++) o[j] = f2bf(acc[i][j] * z);
        *(v4u*)&out[((size_t)(t0 + r)) * DMODEL + h * HDIM + tx * 4] = o;  // 8B store
    }
}

// ---------------------------------------------------------------------------
__global__ __launch_bounds__(256) void ln_kernel(const float* in, float* outF,
                                                 ushort_t* outB,
                                                 const float* __restrict__ g,
                                                 const float* __restrict__ b) {
    const int row = blockIdx.x;
    const int tid = threadIdx.x;
    const float4 v = ((const float4*)(in + (size_t)row * DMODEL))[tid];
    float s = v.x + v.y + v.z + v.w;
    float ss = v.x * v.x + v.y * v.y + v.z * v.z + v.w * v.w;
    #pragma unroll
    for (int off = 32; off; off >>= 1) {
        s += __shfl_down(s, off);
        ss += __shfl_down(ss, off);
    }
    __shared__ float red[8];
    const int lane = tid & 63, w = tid >> 6;
    if (lane == 0) { red[w * 2] = s; red[w * 2 + 1] = ss; }
    __syncthreads();
    s = red[0] + red[2] + red[4] + red[6];
    ss = red[1] + red[3] + red[5] + red[7];
    const float mu = s * (1.f / DMODEL);
    const float var = ss * (1.f / DMODEL) - mu * mu;
    const float rs = rsqrtf(var + 1e-5f);
    const float4 gg = ((const float4*)g)[tid];
    const float4 bb = ((const float4*)b)[tid];
    float4 o;
    o.x = (v.x - mu) * rs * gg.x + bb.x;
    o.y = (v.y - mu) * rs * gg.y + bb.y;
    o.z = (v.z - mu) * rs * gg.z + bb.z;
    o.w = (v.w - mu) * rs * gg.w + bb.w;
    ((float4*)(outF + (size_t)row * DMODEL))[tid] = o;
    if (outB) {
        v4u ob;
        ob[0] = f2bf(o.x); ob[1] = f2bf(o.y); ob[2] = f2bf(o.z); ob[3] = f2bf(o.w);
        *(v4u*)(outB + (size_t)row * DMODEL + tid * 4) = ob;
    }
}

// ---------------------------------------------------------------------------
extern "C" void kernel_launch(void* const* d_in, const int* in_sizes, int n_in,
                              void* d_out, int out_size, void* d_ws, size_t ws_size,
                              hipStream_t stream) {
    const float* src = (const float*)d_in[0];
    const unsigned char* mask = (const unsigned char*)d_in[1];
    const float* Wq = (const float*)d_in[2];
    const float* bq = (const float*)d_in[3];
    const float* Wk = (const float*)d_in[4];
    const float* bk = (const float*)d_in[5];
    const float* Wv = (const float*)d_in[6];
    const float* bv = (const float*)d_in[7];
    const float* Wo = (const float*)d_in[8];
    const float* bo = (const float*)d_in[9];
    const float* W1 = (const float*)d_in[10];
    const float* b1 = (const float*)d_in[11];
    const float* W2 = (const float*)d_in[12];
    const float* b2 = (const float*)d_in[13];
    const float* g1 = (const float*)d_in[14];
    const float* be1 = (const float*)d_in[15];
    const float* g2 = (const float*)d_in[16];
    const float* be2 = (const float*)d_in[17];

    float* xout = (float*)d_out;  // fp32 residual-stream master

    char* ws = (char*)d_ws;
    size_t off = 0;
    auto alloc = [&](size_t bytes) -> void* {
        void* p = (void*)(ws + off);
        off += (bytes + 255) & ~(size_t)255;
        return p;
    };
    const size_t DD = (size_t)DMODEL * DMODEL;
    const size_t FD = (size_t)DFF * DMODEL;
    const size_t MD = (size_t)MTOK * DMODEL;

    ushort_t* wqkv_bf = (ushort_t*)alloc(NLAYER * 3 * DD * 2);  // [L][3][D][D]
    ushort_t* wo_bf = (ushort_t*)alloc(NLAYER * DD * 2);
    ushort_t* w1r = (ushort_t*)alloc(FD * 2);
    ushort_t* w2r = (ushort_t*)alloc(FD * 2);
    ushort_t* xbf = (ushort_t*)alloc(MD * 2);
    ushort_t* Qb = (ushort_t*)alloc(MD * 2);
    ushort_t* Kb = (ushort_t*)alloc(MD * 2);
    ushort_t* Vb = (ushort_t*)alloc(MD * 2);
    (void)alloc(MD * 2);          // hb (=Qb) overlay spans MTOK*DFF bf16
    ushort_t* hb = Qb;
    float* Ksum = (float*)alloc((size_t)NBATCH * DMODEL * 4);
    float* KVp = (float*)alloc((size_t)8 * 64 * 4096 * 4);
    float* KVb = (float*)alloc((size_t)64 * 4096 * 4);
    int* lens = (int*)alloc(256);
    if (off > ws_size) return;

    cvt_qkv<<<dim3((unsigned)((NLAYER * DD) / 1024)), dim3(256), 0, stream>>>(Wq, Wk, Wv, wqkv_bf);
    cvt_bf16<<<dim3((unsigned)((NLAYER * DD) / 1024)), dim3(256), 0, stream>>>(Wo, wo_bf, (int)(NLAYER * DD));
    lens_kernel<<<dim3(1), dim3(256), 0, stream>>>(mask, lens);
    cvt_bf16<<<dim3((unsigned)(MD / 1024)), dim3(256), 0, stream>>>(src, xbf, (int)MD);

    const dim3 blk(256);
    const dim3 gQKV((MTOK / 128) * (3 * DMODEL / 128));  // 3072 blocks
    const dim3 gD((MTOK / 128) * (DMODEL / 128));        // 1024 blocks
    const dim3 gF((MTOK / 128) * (DFF / 128));           // 4096 blocks

    for (int l = 0; l < NLAYER; l++) {
        const ushort_t* wqkvl = wqkv_bf + (size_t)l * 3 * DD;
        const ushort_t* wol = wo_bf + l * DD;
        const float* bql = bq + l * DMODEL;
        const float* bkl = bk + l * DMODEL;
        const float* bvl = bv + l * DMODEL;
        const float* bol = bo + l * DMODEL;
        const float* b1l = b1 + l * DFF;
        const float* b2l = b2 + l * DMODEL;
        const float* g1l = g1 + l * DMODEL;
        const float* be1l = be1 + l * DMODEL;
        const float* g2l = g2 + l * DMODEL;
        const float* be2l = be2 + l * DMODEL;
        const float* resx = (l == 0) ? src : xout;

        // fused Q/K/V projection with feature map + mask
        gemm_bt<EPI_QKV><<<gQKV, blk, 0, stream>>>(xbf, wqkvl, bql, bkl, bvl,
            nullptr, lens, Qb, Kb, Vb, nullptr, MTOK, 3 * DMODEL, DMODEL);

        // linear-attention core
        ksum_kernel<<<dim3(64), blk, 0, stream>>>(Kb, Ksum);
        kv_part<<<dim3(8, 64), blk, 0, stream>>>(Kb, Vb, KVp);
        kv_reduce<<<dim3(64 * 4096 / 256), blk, 0, stream>>>(KVp, KVb);
        attn_kernel<<<dim3(64, 64), blk, 0, stream>>>(Qb, KVb, Ksum, Kb);  // attn -> Kb

        // output projection + residual (fp32), then LN1 + bf16 copy
        gemm_bt<EPI_RES><<<gD, blk, 0, stream>>>(Kb, wol, bol, nullptr, nullptr,
            resx, lens, nullptr, nullptr, nullptr, xout, MTOK, DMODEL, DMODEL);
        ln_kernel<<<dim3(MTOK), blk, 0, stream>>>(xout, xout, xbf, g1l, be1l);

        // FFN
        cvt_bf16<<<dim3((unsigned)(FD / 1024)), blk, 0, stream>>>(W1 + l * FD, w1r, (int)FD);
        gemm_bt<EPI_GELU><<<gF, blk, 0, stream>>>(xbf, w1r, b1l, nullptr, nullptr,
            nullptr, lens, hb, nullptr, nullptr, nullptr, MTOK, DFF, DMODEL);
        cvt_bf16<<<dim3((unsigned)(FD / 1024)), blk, 0, stream>>>(W2 + l * FD, w2r, (int)FD);
        gemm_bt<EPI_RES><<<gD, blk, 0, stream>>>(hb, w2r, b2l, nullptr, nullptr,
            xout, lens, nullptr, nullptr, nullptr, xout, MTOK, DMODEL, DFF);
        ln_kernel<<<dim3(MTOK), blk, 0, stream>>>(xout, xout, (l == NLAYER - 1) ? nullptr : xbf, g2l, be2l);
    }
}

// Round 5
// 3359.199 us; speedup vs baseline: 1.2452x; 1.0902x over previous
//
#include <hip/hip_runtime.h>
#include <cstdint>

typedef unsigned short ushort_t;
typedef short v8s __attribute__((ext_vector_type(8)));
typedef float v4f __attribute__((ext_vector_type(4)));
typedef unsigned short v4u __attribute__((ext_vector_type(4)));

#define DMODEL 1024
#define DFF 4096
#define SEQ 4096
#define NBATCH 4
#define NHEAD 16
#define HDIM 64
#define NLAYER 4
#define MTOK (NBATCH*SEQ)   // 16384

#define EPI_QKV 0
#define EPI_RES 3
#define EPI_GELU 4

__device__ __forceinline__ float bf2f(ushort_t u) {
    unsigned v = ((unsigned)u) << 16; float f; __builtin_memcpy(&f, &v, 4); return f;
}
__device__ __forceinline__ ushort_t f2bf(float f) {
    unsigned u; __builtin_memcpy(&u, &f, 4);
    u = (u + 0x7fffu + ((u >> 16) & 1u)) >> 16;
    return (ushort_t)u;
}

// exact-form GELU with A&S 7.1.26 erf approximation (|err| <= 1.5e-7).
__device__ __forceinline__ float gelu_f(float x) {
    const float y = x * 0.70710678118f;
    const float ay = fabsf(y);
    const float t = __builtin_amdgcn_rcpf(1.f + 0.3275911f * ay);
    const float p = t * (0.254829592f + t * (-0.284496736f + t * (1.421413741f +
                    t * (-1.453152027f + t * 1.061405429f))));
    const float e = __expf(-y * y);
    float er = 1.f - p * e;
    er = (y < 0.f) ? -er : er;
    return 0.5f * x * (1.f + er);
}

// ---------------------------------------------------------------------------
__global__ __launch_bounds__(256) void cvt_bf16(const float* __restrict__ in,
                                                ushort_t* __restrict__ out, int n) {
    int i = (blockIdx.x * 256 + threadIdx.x) * 4;
    if (i >= n) return;
    float4 v = *(const float4*)(in + i);
    v4u o;
    o[0] = f2bf(v.x); o[1] = f2bf(v.y); o[2] = f2bf(v.z); o[3] = f2bf(v.w);
    *(v4u*)(out + i) = o;
}

// pack Wq/Wk/Wv (each [L][D][D] fp32) into bf16 [L][3][D][D]
__global__ __launch_bounds__(256) void cvt_qkv(const float* __restrict__ Wq,
                                               const float* __restrict__ Wk,
                                               const float* __restrict__ Wv,
                                               ushort_t* __restrict__ out) {
    const size_t DD = (size_t)DMODEL * DMODEL;
    size_t i = ((size_t)blockIdx.x * 256 + threadIdx.x) * 4;
    int l = (int)(i / DD);
    size_t r = i % DD;
    const float* srcs[3] = { Wq + l * DD + r, Wk + l * DD + r, Wv + l * DD + r };
    #pragma unroll
    for (int s = 0; s < 3; s++) {
        float4 v = *(const float4*)srcs[s];
        v4u o;
        o[0] = f2bf(v.x); o[1] = f2bf(v.y); o[2] = f2bf(v.z); o[3] = f2bf(v.w);
        *(v4u*)(out + ((size_t)l * 3 + s) * DD + r) = o;
    }
}

// ---------------------------------------------------------------------------
__global__ __launch_bounds__(256) void lens_kernel(const unsigned char* __restrict__ mask,
                                                   int* __restrict__ lens) {
    int lane = threadIdx.x & 63, w = threadIdx.x >> 6;
    int cnt = 0;
    for (int i = lane; i < SEQ; i += 64) cnt += (mask[w * SEQ + i] != 0) ? 1 : 0;
    #pragma unroll
    for (int off = 32; off; off >>= 1) cnt += __shfl_down(cnt, off);
    if (lane == 0) lens[w] = SEQ - cnt;
}

// ---------------------------------------------------------------------------
// GEMM: C[M,N] = A[M,K] @ B[N,K]^T, bf16 in, fp32 acc, fused epilogues.
// 128x128 tile, 4 waves of 64x64, BK=64.
// PIPELINED (hipBLASLt/AITER shape): buffer_load -> VGPR -> ds_write with
// ping-pong LDS buffers. Register destinations mean __syncthreads only drains
// lgkmcnt; the 8 global loads for tile t+1 stay in flight across the barrier
// and the MFMA phase of tile t (the m97 vmcnt(0) drain is gone).
// One barrier per 32 MFMA; t-1's readers are fenced by the previous barrier.
// XCD-aware remap + 8-chunk XOR swizzle (conflict-free) retained.
// ---------------------------------------------------------------------------
template <int EPI>
__global__ __launch_bounds__(256, 2) void gemm_bt(
    const ushort_t* __restrict__ A, const ushort_t* __restrict__ B,
    const float* __restrict__ bias, const float* __restrict__ bias2,
    const float* __restrict__ bias3, const float* res,
    const int* __restrict__ lens,
    ushort_t* __restrict__ outB, ushort_t* __restrict__ outB2,
    ushort_t* __restrict__ outB3, float* outF,
    int M, int N, int K)
{
    __shared__ __align__(16) ushort_t As[2][128 * 64];
    __shared__ __align__(16) ushort_t Bs[2][128 * 64];

    const int tid = threadIdx.x;
    const int lane = tid & 63;
    const int wave = tid >> 6;
    const int nb = N >> 7;
    // XCD-aware remap (dispatch round-robins XCD = blockIdx.x % 8)
    const int xcd = blockIdx.x & 7;
    const int q = blockIdx.x >> 3;
    const int bm = (q / nb) * 8 + xcd;   // M/128 = 128, divisible by 8
    const int bn = q % nb;
    const int wm = (wave >> 1) * 64;
    const int wn = (wave & 1) * 64;
    const int lr = lane & 15;
    const int lq = lane >> 4;  // 0..3

    v4f acc[4][4];
    #pragma unroll
    for (int i = 0; i < 4; i++)
        #pragma unroll
        for (int j = 0; j < 4; j++) acc[i][j] = (v4f)0.f;

    // staging geometry: load i covers rows i*32 + (tid>>3); 8 chunks (16B) per
    // 64-elem row, source chunk XOR-swizzled so LDS slot s of row r holds
    // global chunk s^(r&7).
    const int srow = tid >> 3;               // 0..31
    const int schunk = (tid & 7) ^ (srow & 7);
    const ushort_t* Ag = A + (size_t)(bm * 128 + srow) * K + schunk * 8;
    const ushort_t* Bg = B + (size_t)(bn * 128 + srow) * K + schunk * 8;
    const size_t rstep = (size_t)32 * K;     // 32 rows per staging load
    const int sdst = tid * 8;                // LDS ushort offset

    // fragment LDS ushort offsets (k-invariant, read-side XOR)
    int a_off[2][4], b_off[2][4];
    #pragma unroll
    for (int h = 0; h < 2; h++)
        #pragma unroll
        for (int i = 0; i < 4; i++) {
            const int ra = wm + i * 16 + lr;
            a_off[h][i] = ra * 64 + (((h * 4 + lq) ^ (ra & 7)) * 8);
            const int rb = wn + i * 16 + lr;
            b_off[h][i] = rb * 64 + (((h * 4 + lq) ^ (rb & 7)) * 8);
        }

    // prologue: load tile 0 into registers
    v8s ra[4], rb[4];
    #pragma unroll
    for (int i = 0; i < 4; i++) ra[i] = *(const v8s*)(Ag + i * rstep);
    #pragma unroll
    for (int i = 0; i < 4; i++) rb[i] = *(const v8s*)(Bg + i * rstep);

    const int iters = K >> 6;
    int p = 0;
    for (int t = 0; t < iters; ++t) {
        // stage tile t into LDS buf p (waits only on tile t's loads,
        // which have been in flight for a full iteration)
        #pragma unroll
        for (int i = 0; i < 4; i++) *(v8s*)&As[p][sdst + i * 2048] = ra[i];
        #pragma unroll
        for (int i = 0; i < 4; i++) *(v8s*)&Bs[p][sdst + i * 2048] = rb[i];
        // issue tile t+1 loads (fly across the barrier + MFMA phase)
        if (t + 1 < iters) {
            const int k0 = (t + 1) << 6;
            #pragma unroll
            for (int i = 0; i < 4; i++) ra[i] = *(const v8s*)(Ag + i * rstep + k0);
            #pragma unroll
            for (int i = 0; i < 4; i++) rb[i] = *(const v8s*)(Bg + i * rstep + k0);
        }
        __syncthreads();   // lgkm drain only; next iter writes the OTHER buffer
        #pragma unroll
        for (int h = 0; h < 2; h++) {
            v8s af[4], bfr[4];
            #pragma unroll
            for (int i = 0; i < 4; i++) af[i] = *(const v8s*)&As[p][a_off[h][i]];
            #pragma unroll
            for (int j = 0; j < 4; j++) bfr[j] = *(const v8s*)&Bs[p][b_off[h][j]];
            #pragma unroll
            for (int i = 0; i < 4; i++)
                #pragma unroll
                for (int j = 0; j < 4; j++)
                    acc[i][j] = __builtin_amdgcn_mfma_f32_16x16x32_bf16(af[i], bfr[j], acc[i][j], 0, 0, 0);
        }
        p ^= 1;
    }

    // epilogue: C/D layout col = lane&15, row = (lane>>4)*4 + reg
    const int row0 = bm * 128 + wm + lq * 4;
    const int col0 = bn * 128 + wn + lr;

    const int seg = bn >> 3;   // EPI_QKV: block-uniform Q/K/V segment
    ushort_t* qkv_out = (EPI == EPI_QKV)
        ? (seg == 0 ? outB : (seg == 1 ? outB2 : outB3)) : outB;
    const float* qkv_bias = (EPI == EPI_QKV)
        ? (seg == 0 ? bias : (seg == 1 ? bias2 : bias3)) : bias;
    const int blen = (EPI == EPI_QKV) ? lens[bm >> 5] : 0;

    #pragma unroll
    for (int i = 0; i < 4; i++) {
        #pragma unroll
        for (int j = 0; j < 4; j++) {
            const int gn = col0 + j * 16;
            const float bsv = (EPI == EPI_QKV) ? qkv_bias[gn & 1023] : bias[gn];
            #pragma unroll
            for (int r = 0; r < 4; r++) {
                const int gm = row0 + i * 16 + r;
                float v = acc[i][j][r] + bsv;
                if (EPI == EPI_QKV) {
                    const size_t oi = (size_t)gm * DMODEL + (gn & 1023);
                    if (seg == 2) {
                        qkv_out[oi] = f2bf(v);                    // V
                    } else {
                        float e = v > 0.f ? v + 1.f : __expf(v);  // elu+1
                        if (seg == 1 && (gm & 4095) >= blen) e = 0.f;  // K mask
                        qkv_out[oi] = f2bf(e);
                    }
                } else if (EPI == EPI_RES) {
                    const size_t oi = (size_t)gm * N + gn;
                    outF[oi] = v + res[oi];
                } else {  // EPI_GELU (plain store: nontemporal 2x'd HBM writes in R4)
                    const size_t oi = (size_t)gm * N + gn;
                    outB[oi] = f2bf(gelu_f(v));
                }
            }
        }
    }
}

// ---------------------------------------------------------------------------
__global__ __launch_bounds__(256) void ksum_kernel(const ushort_t* __restrict__ K,
                                                   float* __restrict__ out) {
    const int blk = blockIdx.x;
    const int n = blk >> 4, cg = blk & 15;
    const int tx = threadIdx.x & 63, ty = threadIdx.x >> 6;
    const int col = cg * 64 + tx;
    const ushort_t* p = K + ((size_t)n * SEQ + ty * 1024) * DMODEL + col;
    float a = 0.f;
    for (int s = 0; s < 1024; s++) a += bf2f(p[(size_t)s * DMODEL]);
    __shared__ float red[4][64];
    red[ty][tx] = a;
    __syncthreads();
    if (ty == 0) out[n * DMODEL + col] = red[0][tx] + red[1][tx] + red[2][tx] + red[3][tx];
}

// ---------------------------------------------------------------------------
__global__ __launch_bounds__(256) void kv_part(const ushort_t* __restrict__ K,
                                               const ushort_t* __restrict__ V,
                                               float* __restrict__ part) {
    const int chunk = blockIdx.x, nh = blockIdx.y;
    const int n = nh >> 4, h = nh & 15;
    const int tid = threadIdx.x;
    const int tm = tid >> 4, td = tid & 15;
    __shared__ float Ks[16][68];
    __shared__ float Vs[16][68];
    float acc[4][4] = {};
    const int s0 = chunk * 512;
    for (int sb = 0; sb < 512; sb += 16) {
        __syncthreads();
        for (int idx = tid; idx < 1024; idx += 256) {
            const int r = idx >> 6, c = idx & 63;
            const size_t gpos = ((size_t)(n * SEQ + s0 + sb + r)) * DMODEL + h * HDIM + c;
            Ks[r][c] = bf2f(K[gpos]);
            Vs[r][c] = bf2f(V[gpos]);
        }
        __syncthreads();
        #pragma unroll
        for (int s = 0; s < 16; s++) {
            float kv[4], vv[4];
            #pragma unroll
            for (int j = 0; j < 4; j++) kv[j] = Ks[s][td * 4 + j];
            #pragma unroll
            for (int i = 0; i < 4; i++) vv[i] = Vs[s][tm * 4 + i];
            #pragma unroll
            for (int i = 0; i < 4; i++)
                #pragma unroll
                for (int j = 0; j < 4; j++)
                    acc[i][j] += vv[i] * kv[j];
        }
    }
    float* o = part + ((size_t)chunk * 64 + nh) * 4096;
    #pragma unroll
    for (int i = 0; i < 4; i++)
        #pragma unroll
        for (int j = 0; j < 4; j++)
            o[(tm * 4 + i) * 64 + td * 4 + j] = acc[i][j];
}

__global__ __launch_bounds__(256) void kv_reduce(const float* __restrict__ part,
                                                 float* __restrict__ KV) {
    const int gid = blockIdx.x * 256 + threadIdx.x;
    float a = 0.f;
    #pragma unroll
    for (int c = 0; c < 8; c++) a += part[(size_t)c * (64 * 4096) + gid];
    KV[gid] = a;
}

// ---------------------------------------------------------------------------
__global__ __launch_bounds__(256) void attn_kernel(const ushort_t* __restrict__ Q,
                                                   const float* __restrict__ KV,
                                                   const float* __restrict__ Ksum,
                                                   ushort_t* __restrict__ out) {
    const int bx = blockIdx.x, nh = blockIdx.y;
    const int n = nh >> 4, h = nh & 15;
    const int tid = threadIdx.x;
    const int ty = tid >> 4, tx = tid & 15;
    __shared__ float KVs[64][65];
    __shared__ float Qs[64][65];
    __shared__ float Zs[64];
    const int t0 = n * SEQ + bx * 64;
    for (int idx = tid; idx < 4096; idx += 256) {
        const int r = idx >> 6, c = idx & 63;
        KVs[r][c] = KV[(size_t)nh * 4096 + idx];
        Qs[r][c] = bf2f(Q[((size_t)(t0 + r)) * DMODEL + h * HDIM + c]);
    }
    __syncthreads();
    if (tid < 64) {
        const float* ks = Ksum + n * DMODEL + h * HDIM;
        float a = 0.f;
        #pragma unroll
        for (int d = 0; d < 64; d++) a += Qs[tid][d] * ks[d];
        Zs[tid] = 1.f / (a + 1e-6f);
    }
    __syncthreads();
    float acc[4][4] = {};
    for (int d = 0; d < 64; d++) {
        float qv[4], kv[4];
        #pragma unroll
        for (int i = 0; i < 4; i++) qv[i] = Qs[ty * 4 + i][d];
        #pragma unroll
        for (int j = 0; j < 4; j++) kv[j] = KVs[tx * 4 + j][d];
        #pragma unroll
        for (int i = 0; i < 4; i++)
            #pragma unroll
            for (int j = 0; j < 4; j++)
                acc[i][j] += qv[i] * kv[j];
    }
    #pragma unroll
    for (int i = 0; i < 4; i++) {
        const int r = ty * 4 + i;
        const float z = Zs[r];
        v4u o;
        #pragma unroll
        for (int j = 0; j < 4; j++) o[j] = f2bf(acc[i][j] * z);
        *(v4u*)&out[((size_t)(t0 + r)) * DMODEL + h * HDIM + tx * 4] = o;  // 8B store
    }
}

// ---------------------------------------------------------------------------
__global__ __launch_bounds__(256) void ln_kernel(const float* in, float* outF,
                                                 ushort_t* outB,
                                                 const float* __restrict__ g,
                                                 const float* __restrict__ b) {
    const int row = blockIdx.x;
    const int tid = threadIdx.x;
    const float4 v = ((const float4*)(in + (size_t)row * DMODEL))[tid];
    float s = v.x + v.y + v.z + v.w;
    float ss = v.x * v.x + v.y * v.y + v.z * v.z + v.w * v.w;
    #pragma unroll
    for (int off = 32; off; off >>= 1) {
        s += __shfl_down(s, off);
        ss += __shfl_down(ss, off);
    }
    __shared__ float red[8];
    const int lane = tid & 63, w = tid >> 6;
    if (lane == 0) { red[w * 2] = s; red[w * 2 + 1] = ss; }
    __syncthreads();
    s = red[0] + red[2] + red[4] + red[6];
    ss = red[1] + red[3] + red[5] + red[7];
    const float mu = s * (1.f / DMODEL);
    const float var = ss * (1.f / DMODEL) - mu * mu;
    const float rs = rsqrtf(var + 1e-5f);
    const float4 gg = ((const float4*)g)[tid];
    const float4 bb = ((const float4*)b)[tid];
    float4 o;
    o.x = (v.x - mu) * rs * gg.x + bb.x;
    o.y = (v.y - mu) * rs * gg.y + bb.y;
    o.z = (v.z - mu) * rs * gg.z + bb.z;
    o.w = (v.w - mu) * rs * gg.w + bb.w;
    ((float4*)(outF + (size_t)row * DMODEL))[tid] = o;
    if (outB) {
        v4u ob;
        ob[0] = f2bf(o.x); ob[1] = f2bf(o.y); ob[2] = f2bf(o.z); ob[3] = f2bf(o.w);
        *(v4u*)(outB + (size_t)row * DMODEL + tid * 4) = ob;
    }
}

// ---------------------------------------------------------------------------
extern "C" void kernel_launch(void* const* d_in, const int* in_sizes, int n_in,
                              void* d_out, int out_size, void* d_ws, size_t ws_size,
                              hipStream_t stream) {
    const float* src = (const float*)d_in[0];
    const unsigned char* mask = (const unsigned char*)d_in[1];
    const float* Wq = (const float*)d_in[2];
    const float* bq = (const float*)d_in[3];
    const float* Wk = (const float*)d_in[4];
    const float* bk = (const float*)d_in[5];
    const float* Wv = (const float*)d_in[6];
    const float* bv = (const float*)d_in[7];
    const float* Wo = (const float*)d_in[8];
    const float* bo = (const float*)d_in[9];
    const float* W1 = (const float*)d_in[10];
    const float* b1 = (const float*)d_in[11];
    const float* W2 = (const float*)d_in[12];
    const float* b2 = (const float*)d_in[13];
    const float* g1 = (const float*)d_in[14];
    const float* be1 = (const float*)d_in[15];
    const float* g2 = (const float*)d_in[16];
    const float* be2 = (const float*)d_in[17];

    float* xout = (float*)d_out;  // fp32 residual-stream master

    char* ws = (char*)d_ws;
    size_t off = 0;
    auto alloc = [&](size_t bytes) -> void* {
        void* p = (void*)(ws + off);
        off += (bytes + 255) & ~(size_t)255;
        return p;
    };
    const size_t DD = (size_t)DMODEL * DMODEL;
    const size_t FD = (size_t)DFF * DMODEL;
    const size_t MD = (size_t)MTOK * DMODEL;

    ushort_t* wqkv_bf = (ushort_t*)alloc(NLAYER * 3 * DD * 2);  // [L][3][D][D]
    ushort_t* wo_bf = (ushort_t*)alloc(NLAYER * DD * 2);
    ushort_t* w1r = (ushort_t*)alloc(FD * 2);
    ushort_t* w2r = (ushort_t*)alloc(FD * 2);
    ushort_t* xbf = (ushort_t*)alloc(MD * 2);
    ushort_t* Qb = (ushort_t*)alloc(MD * 2);
    ushort_t* Kb = (ushort_t*)alloc(MD * 2);
    ushort_t* Vb = (ushort_t*)alloc(MD * 2);
    (void)alloc(MD * 2);          // hb (=Qb) overlay spans MTOK*DFF bf16
    ushort_t* hb = Qb;
    float* Ksum = (float*)alloc((size_t)NBATCH * DMODEL * 4);
    float* KVp = (float*)alloc((size_t)8 * 64 * 4096 * 4);
    float* KVb = (float*)alloc((size_t)64 * 4096 * 4);
    int* lens = (int*)alloc(256);
    if (off > ws_size) return;

    cvt_qkv<<<dim3((unsigned)((NLAYER * DD) / 1024)), dim3(256), 0, stream>>>(Wq, Wk, Wv, wqkv_bf);
    cvt_bf16<<<dim3((unsigned)((NLAYER * DD) / 1024)), dim3(256), 0, stream>>>(Wo, wo_bf, (int)(NLAYER * DD));
    lens_kernel<<<dim3(1), dim3(256), 0, stream>>>(mask, lens);
    cvt_bf16<<<dim3((unsigned)(MD / 1024)), dim3(256), 0, stream>>>(src, xbf, (int)MD);

    const dim3 blk(256);
    const dim3 gQKV((MTOK / 128) * (3 * DMODEL / 128));  // 3072 blocks
    const dim3 gD((MTOK / 128) * (DMODEL / 128));        // 1024 blocks
    const dim3 gF((MTOK / 128) * (DFF / 128));           // 4096 blocks

    for (int l = 0; l < NLAYER; l++) {
        const ushort_t* wqkvl = wqkv_bf + (size_t)l * 3 * DD;
        const ushort_t* wol = wo_bf + l * DD;
        const float* bql = bq + l * DMODEL;
        const float* bkl = bk + l * DMODEL;
        const float* bvl = bv + l * DMODEL;
        const float* bol = bo + l * DMODEL;
        const float* b1l = b1 + l * DFF;
        const float* b2l = b2 + l * DMODEL;
        const float* g1l = g1 + l * DMODEL;
        const float* be1l = be1 + l * DMODEL;
        const float* g2l = g2 + l * DMODEL;
        const float* be2l = be2 + l * DMODEL;
        const float* resx = (l == 0) ? src : xout;

        // fused Q/K/V projection with feature map + mask
        gemm_bt<EPI_QKV><<<gQKV, blk, 0, stream>>>(xbf, wqkvl, bql, bkl, bvl,
            nullptr, lens, Qb, Kb, Vb, nullptr, MTOK, 3 * DMODEL, DMODEL);

        // linear-attention core
        ksum_kernel<<<dim3(64), blk, 0, stream>>>(Kb, Ksum);
        kv_part<<<dim3(8, 64), blk, 0, stream>>>(Kb, Vb, KVp);
        kv_reduce<<<dim3(64 * 4096 / 256), blk, 0, stream>>>(KVp, KVb);
        attn_kernel<<<dim3(64, 64), blk, 0, stream>>>(Qb, KVb, Ksum, Kb);  // attn -> Kb

        // output projection + residual (fp32), then LN1 + bf16 copy
        gemm_bt<EPI_RES><<<gD, blk, 0, stream>>>(Kb, wol, bol, nullptr, nullptr,
            resx, lens, nullptr, nullptr, nullptr, xout, MTOK, DMODEL, DMODEL);
        ln_kernel<<<dim3(MTOK), blk, 0, stream>>>(xout, xout, xbf, g1l, be1l);

        // FFN
        cvt_bf16<<<dim3((unsigned)(FD / 1024)), blk, 0, stream>>>(W1 + l * FD, w1r, (int)FD);
        gemm_bt<EPI_GELU><<<gF, blk, 0, stream>>>(xbf, w1r, b1l, nullptr, nullptr,
            nullptr, lens, hb, nullptr, nullptr, nullptr, MTOK, DFF, DMODEL);
        cvt_bf16<<<dim3((unsigned)(FD / 1024)), blk, 0, stream>>>(W2 + l * FD, w2r, (int)FD);
        gemm_bt<EPI_RES><<<gD, blk, 0, stream>>>(hb, w2r, b2l, nullptr, nullptr,
            xout, lens, nullptr, nullptr, nullptr, xout, MTOK, DMODEL, DFF);
        ln_kernel<<<dim3(MTOK), blk, 0, stream>>>(xout, xout, (l == NLAYER - 1) ? nullptr : xbf, g2l, be2l);
    }
}